// Round 1
// baseline (43367.719 us; speedup 1.0000x reference)
//
#include <hip/hip_runtime.h>
#include <cstddef>

// ---------------- model constants (from reference setup_inputs) ----------------
#define S_LEN   4096
#define DMODEL  768
#define NHEAD   12
#define DHEAD   64
#define FDIM    3072
#define NLAYER  12
#define WIN     256        // one-sided window
#define NGLOB   8
#define GSTRIDE 512        // win_len = S/NW; global tokens at multiples of 512

// ---------------- reductions ----------------
__device__ __forceinline__ float wave_sum(float v) {
#pragma unroll
  for (int off = 32; off > 0; off >>= 1) v += __shfl_xor(v, off);
  return v;
}

// 256-thread block sum; sbuf must be float[4] shared
__device__ __forceinline__ float block_sum256(float v, float* sbuf) {
  v = wave_sum(v);
  int w = threadIdx.x >> 6;
  __syncthreads();                    // protect sbuf reuse across calls
  if ((threadIdx.x & 63) == 0) sbuf[w] = v;
  __syncthreads();
  return sbuf[0] + sbuf[1] + sbuf[2] + sbuf[3];
}

// ---------------- embedding + LN ----------------
__global__ __launch_bounds__(256) void embed_ln_kernel(
    const int* __restrict__ x, const float* __restrict__ wemb,
    const float* __restrict__ pemb, const float* __restrict__ gg,
    const float* __restrict__ bb, float* __restrict__ h) {
  __shared__ float sbuf[4];
  int s = blockIdx.x;
  int tid = threadIdx.x;
  int idx = x[s];
  float vals[3];
#pragma unroll
  for (int i = 0; i < 3; i++) {
    int d = tid + i * 256;
    vals[i] = wemb[(size_t)idx * DMODEL + d] + pemb[(size_t)s * DMODEL + d];
  }
  float mean = block_sum256(vals[0] + vals[1] + vals[2], sbuf) * (1.0f / 768.0f);
  float sq = 0.f;
#pragma unroll
  for (int i = 0; i < 3; i++) { float t = vals[i] - mean; sq += t * t; }
  float var = block_sum256(sq, sbuf) * (1.0f / 768.0f);
  float inv = rsqrtf(var + 1e-5f);
#pragma unroll
  for (int i = 0; i < 3; i++) {
    int d = tid + i * 256;
    h[(size_t)s * DMODEL + d] = (vals[i] - mean) * inv * gg[d] + bb[d];
  }
}

// ---------------- residual + LN (in place on h) ----------------
__global__ __launch_bounds__(256) void add_ln_kernel(
    float* __restrict__ h, const float* __restrict__ r,
    const float* __restrict__ gg, const float* __restrict__ bb) {
  __shared__ float sbuf[4];
  int s = blockIdx.x;
  int tid = threadIdx.x;
  float vals[3];
#pragma unroll
  for (int i = 0; i < 3; i++) {
    int d = tid + i * 256;
    vals[i] = h[(size_t)s * DMODEL + d] + r[(size_t)s * DMODEL + d];
  }
  float mean = block_sum256(vals[0] + vals[1] + vals[2], sbuf) * (1.0f / 768.0f);
  float sq = 0.f;
#pragma unroll
  for (int i = 0; i < 3; i++) { float t = vals[i] - mean; sq += t * t; }
  float var = block_sum256(sq, sbuf) * (1.0f / 768.0f);
  float inv = rsqrtf(var + 1e-5f);
#pragma unroll
  for (int i = 0; i < 3; i++) {
    int d = tid + i * 256;
    h[(size_t)s * DMODEL + d] = (vals[i] - mean) * inv * gg[d] + bb[d];
  }
}

// ---------------- generic fp32 GEMM: C[M,N] = A[M,K] @ W[K,N] + bias, opt. GELU ----
// 64x64 tile, BK=16, 256 threads, 4x4 per thread.
template <int ACT>
__global__ __launch_bounds__(256) void gemm_kernel(
    const float* __restrict__ A, const float* __restrict__ W,
    const float* __restrict__ bias, float* __restrict__ C,
    int M, int N, int K) {
  __shared__ float As[16][68];
  __shared__ float Bs[16][68];
  int t = threadIdx.x;
  int tx = t & 15, ty = t >> 4;
  int bm = blockIdx.y * 64, bn = blockIdx.x * 64;
  int ar = t >> 2, akq = (t & 3) << 2;   // A stage: row ar, k-offset akq..akq+3
  int bkk = t >> 4, bc = (t & 15) << 2;  // B stage: k bkk, col bc..bc+3
  float acc[4][4] = {};
  const float* Aptr = A + (size_t)(bm + ar) * K + akq;
  const float* Wptr = W + (size_t)bkk * N + bn + bc;
  for (int kt = 0; kt < K; kt += 16) {
    float4 av = *(const float4*)(Aptr + kt);
    float4 bv = *(const float4*)(Wptr + (size_t)kt * N);
    __syncthreads();
    As[akq + 0][ar] = av.x;
    As[akq + 1][ar] = av.y;
    As[akq + 2][ar] = av.z;
    As[akq + 3][ar] = av.w;
    *(float4*)&Bs[bkk][bc] = bv;
    __syncthreads();
#pragma unroll
    for (int kk = 0; kk < 16; kk++) {
      float4 a = *(const float4*)&As[kk][ty << 2];
      float4 b = *(const float4*)&Bs[kk][tx << 2];
      acc[0][0] += a.x * b.x; acc[0][1] += a.x * b.y; acc[0][2] += a.x * b.z; acc[0][3] += a.x * b.w;
      acc[1][0] += a.y * b.x; acc[1][1] += a.y * b.y; acc[1][2] += a.y * b.z; acc[1][3] += a.y * b.w;
      acc[2][0] += a.z * b.x; acc[2][1] += a.z * b.y; acc[2][2] += a.z * b.z; acc[2][3] += a.z * b.w;
      acc[3][0] += a.w * b.x; acc[3][1] += a.w * b.y; acc[3][2] += a.w * b.z; acc[3][3] += a.w * b.w;
    }
  }
#pragma unroll
  for (int i = 0; i < 4; i++) {
    int row = bm + (ty << 2) + i;
#pragma unroll
    for (int j = 0; j < 4; j++) {
      int col = bn + (tx << 2) + j;
      float r = acc[i][j] + bias[col];
      if (ACT == 1) r = 0.5f * r * (1.0f + erff(r * 0.70710678118654752f));
      C[(size_t)row * N + col] = r;
    }
  }
}

// ---------------- qg projection: qg[g,D] = h[gpos[g]] @ Wqg + bqg ----------------
__global__ __launch_bounds__(256) void qg_proj_kernel(
    const float* __restrict__ h, const float* __restrict__ Wqg,
    const float* __restrict__ bqg, float* __restrict__ qg) {
  __shared__ float hs[DMODEL];
  int gi = blockIdx.x;
  const float* hrow = h + (size_t)gi * GSTRIDE * DMODEL;
  int tid = threadIdx.x;
  for (int i = tid; i < DMODEL; i += 256) hs[i] = hrow[i];
  __syncthreads();
  float a0 = bqg[tid], a1 = bqg[tid + 256], a2 = bqg[tid + 512];
  for (int kk = 0; kk < DMODEL; kk++) {
    float hv = hs[kk];
    a0 += hv * Wqg[(size_t)kk * DMODEL + tid];
    a1 += hv * Wqg[(size_t)kk * DMODEL + tid + 256];
    a2 += hv * Wqg[(size_t)kk * DMODEL + tid + 512];
  }
  qg[gi * DMODEL + tid] = a0;
  qg[gi * DMODEL + tid + 256] = a1;
  qg[gi * DMODEL + tid + 512] = a2;
}

// ---------------- sliding-window attention (one wave per (head, query)) -----------
// ctx[s] for s not a global position: softmax over {8 global keys} U
// {band keys kp in [s-256, s+256], kp valid, kp not global}.
__global__ __launch_bounds__(256) void sliding_attn_kernel(
    const float* __restrict__ q, const float* __restrict__ k,
    const float* __restrict__ v, const int* __restrict__ xmask,
    float* __restrict__ ctx) {
  int wid = blockIdx.x * 4 + (threadIdx.x >> 6);
  int lane = threadIdx.x & 63;
  int hh = wid >> 12;      // / S_LEN
  int s = wid & 4095;
  if ((s & (GSTRIDE - 1)) == 0) return;  // global rows written by global_attn
  int col = hh * DHEAD + lane;
  float qv = q[(size_t)s * DMODEL + col] * 0.125f;  // 1/sqrt(64)
  float m = -1e30f, l = 0.f, acc = 0.f;
#pragma unroll
  for (int gi = 0; gi < NGLOB; gi++) {
    int kp = gi * GSTRIDE;     // mask forced to 1 at global slots
    float d = wave_sum(qv * k[(size_t)kp * DMODEL + col]);
    float vv = v[(size_t)kp * DMODEL + col];
    float mn = fmaxf(m, d);
    float p = __expf(d - mn);
    float al = __expf(m - mn);
    l = l * al + p;
    acc = acc * al + p * vv;
    m = mn;
  }
  int lo = s - WIN; if (lo < 0) lo = 0;
  int hi = s + WIN; if (hi > S_LEN - 1) hi = S_LEN - 1;
  for (int kp = lo; kp <= hi; kp++) {
    if ((kp & (GSTRIDE - 1)) == 0) continue;  // global keys excluded from band
    if (xmask[kp] == 0) continue;
    float d = wave_sum(qv * k[(size_t)kp * DMODEL + col]);
    float vv = v[(size_t)kp * DMODEL + col];
    float mn = fmaxf(m, d);
    float p = __expf(d - mn);
    float al = __expf(m - mn);
    l = l * al + p;
    acc = acc * al + p * vv;
    m = mn;
  }
  ctx[(size_t)s * DMODEL + col] = acc / l;
}

// ---------------- global-token attention (full attention over all S keys) ---------
__global__ __launch_bounds__(256) void global_attn_kernel(
    const float* __restrict__ qg, const float* __restrict__ kg,
    const float* __restrict__ vg, const int* __restrict__ xmask,
    float* __restrict__ ctx) {
  __shared__ float sm[4], sl[4], sacc[4][64];
  int gi = blockIdx.x / NHEAD, hh = blockIdx.x % NHEAD;
  int w = threadIdx.x >> 6, lane = threadIdx.x & 63;
  int col = hh * DHEAD + lane;
  float qv = qg[gi * DMODEL + col] * 0.125f;
  float m = -1e30f, l = 0.f, acc = 0.f;
  for (int s = w * (S_LEN / 4); s < (w + 1) * (S_LEN / 4); s++) {
    bool ok = (xmask[s] != 0) || ((s & (GSTRIDE - 1)) == 0);  // gpos forced valid
    if (!ok) continue;
    float d = wave_sum(qv * kg[(size_t)s * DMODEL + col]);
    float vv = vg[(size_t)s * DMODEL + col];
    float mn = fmaxf(m, d);
    float p = __expf(d - mn);
    float al = __expf(m - mn);
    l = l * al + p;
    acc = acc * al + p * vv;
    m = mn;
  }
  if (lane == 0) { sm[w] = m; sl[w] = l; }
  sacc[w][lane] = acc;
  __syncthreads();
  if (w == 0) {
    float M = fmaxf(fmaxf(sm[0], sm[1]), fmaxf(sm[2], sm[3]));
    float L = 0.f, A = 0.f;
#pragma unroll
    for (int j = 0; j < 4; j++) {
      float al = __expf(sm[j] - M);
      L += sl[j] * al;
      A += sacc[j][lane] * al;
    }
    ctx[(size_t)gi * GSTRIDE * DMODEL + col] = A / L;
  }
}

// ---------------- CLS pooling + output projection -----------------
__global__ __launch_bounds__(128) void cls_out_kernel(
    const float* __restrict__ h, const float* __restrict__ ow,
    const float* __restrict__ ob, float* __restrict__ y) {
  __shared__ float hs[DMODEL];
  int wi = blockIdx.x;
  int tid = threadIdx.x;  // 128
  for (int i = tid; i < DMODEL; i += 128) hs[i] = h[(size_t)wi * GSTRIDE * DMODEL + i];
  __syncthreads();
  float a = ob[tid];
  for (int d = 0; d < DMODEL; d++) a += hs[d] * ow[d * 128 + tid];
  y[wi * 128 + tid] = a;
}

// ---------------- host launch ----------------
extern "C" void kernel_launch(void* const* d_in, const int* in_sizes, int n_in,
                              void* d_out, int out_size, void* d_ws, size_t ws_size,
                              hipStream_t stream) {
  const int*   x      = (const int*)d_in[0];
  const int*   xmask  = (const int*)d_in[1];
  const float* wemb   = (const float*)d_in[2];
  const float* pemb   = (const float*)d_in[3];
  const float* emb_g  = (const float*)d_in[4];
  const float* emb_b  = (const float*)d_in[5];
  const float* Wq     = (const float*)d_in[6];
  const float* bq     = (const float*)d_in[7];
  const float* Wk     = (const float*)d_in[8];
  const float* bk     = (const float*)d_in[9];
  const float* Wv     = (const float*)d_in[10];
  const float* bv     = (const float*)d_in[11];
  const float* Wo     = (const float*)d_in[12];
  const float* bo     = (const float*)d_in[13];
  const float* Wqg    = (const float*)d_in[14];
  const float* bqg    = (const float*)d_in[15];
  const float* Wkg    = (const float*)d_in[16];
  const float* bkg    = (const float*)d_in[17];
  const float* Wvg    = (const float*)d_in[18];
  const float* bvg    = (const float*)d_in[19];
  const float* ln1_g  = (const float*)d_in[20];
  const float* ln1_b  = (const float*)d_in[21];
  const float* W1     = (const float*)d_in[22];
  const float* b1     = (const float*)d_in[23];
  const float* W2     = (const float*)d_in[24];
  const float* b2     = (const float*)d_in[25];
  const float* ln2_g  = (const float*)d_in[26];
  const float* ln2_b  = (const float*)d_in[27];
  const float* out_w  = (const float*)d_in[28];
  const float* out_b  = (const float*)d_in[29];

  const size_t Sz = (size_t)S_LEN * DMODEL;
  float* ws  = (float*)d_ws;
  float* h   = ws;
  float* ctx = ws + 1 * Sz;
  float* tmp = ws + 2 * Sz;
  float* qb  = ws + 3 * Sz;
  float* kb  = ws + 4 * Sz;
  float* vb  = ws + 5 * Sz;
  float* kgb = ws + 6 * Sz;
  float* vgb = ws + 7 * Sz;
  float* qgb = ws + 8 * Sz;
  float* mid = qb;  // FFN intermediate [S, F] aliases q..kg (dead after attention)

  embed_ln_kernel<<<S_LEN, 256, 0, stream>>>(x, wemb, pemb, emb_g, emb_b, h);

  dim3 gD(DMODEL / 64, S_LEN / 64);   // (12, 64)
  dim3 gF(FDIM / 64, S_LEN / 64);     // (48, 64)
  const size_t DD = (size_t)DMODEL * DMODEL;
  const size_t DF = (size_t)DMODEL * FDIM;

  for (int l = 0; l < NLAYER; l++) {
    const float* wq  = Wq  + (size_t)l * DD;  const float* bql  = bq  + (size_t)l * DMODEL;
    const float* wk  = Wk  + (size_t)l * DD;  const float* bkl  = bk  + (size_t)l * DMODEL;
    const float* wv  = Wv  + (size_t)l * DD;  const float* bvl  = bv  + (size_t)l * DMODEL;
    const float* wo  = Wo  + (size_t)l * DD;  const float* bol  = bo  + (size_t)l * DMODEL;
    const float* wqg = Wqg + (size_t)l * DD;  const float* bqgl = bqg + (size_t)l * DMODEL;
    const float* wkg = Wkg + (size_t)l * DD;  const float* bkgl = bkg + (size_t)l * DMODEL;
    const float* wvg = Wvg + (size_t)l * DD;  const float* bvgl = bvg + (size_t)l * DMODEL;
    const float* w1  = W1  + (size_t)l * DF;  const float* b1l  = b1  + (size_t)l * FDIM;
    const float* w2  = W2  + (size_t)l * DF;  const float* b2l  = b2  + (size_t)l * DMODEL;

    gemm_kernel<0><<<gD, 256, 0, stream>>>(h, wq,  bql,  qb,  S_LEN, DMODEL, DMODEL);
    gemm_kernel<0><<<gD, 256, 0, stream>>>(h, wk,  bkl,  kb,  S_LEN, DMODEL, DMODEL);
    gemm_kernel<0><<<gD, 256, 0, stream>>>(h, wv,  bvl,  vb,  S_LEN, DMODEL, DMODEL);
    gemm_kernel<0><<<gD, 256, 0, stream>>>(h, wkg, bkgl, kgb, S_LEN, DMODEL, DMODEL);
    gemm_kernel<0><<<gD, 256, 0, stream>>>(h, wvg, bvgl, vgb, S_LEN, DMODEL, DMODEL);
    qg_proj_kernel<<<NGLOB, 256, 0, stream>>>(h, wqg, bqgl, qgb);

    sliding_attn_kernel<<<(S_LEN * NHEAD) / 4, 256, 0, stream>>>(qb, kb, vb, xmask, ctx);
    global_attn_kernel<<<NGLOB * NHEAD, 256, 0, stream>>>(qgb, kgb, vgb, xmask, ctx);

    gemm_kernel<0><<<gD, 256, 0, stream>>>(ctx, wo, bol, tmp, S_LEN, DMODEL, DMODEL);
    add_ln_kernel<<<S_LEN, 256, 0, stream>>>(h, tmp, ln1_g + (size_t)l * DMODEL, ln1_b + (size_t)l * DMODEL);

    gemm_kernel<1><<<gF, 256, 0, stream>>>(h, w1, b1l, mid, S_LEN, FDIM, DMODEL);
    gemm_kernel<0><<<gD, 256, 0, stream>>>(mid, w2, b2l, tmp, S_LEN, DMODEL, FDIM);
    add_ln_kernel<<<S_LEN, 256, 0, stream>>>(h, tmp, ln2_g + (size_t)l * DMODEL, ln2_b + (size_t)l * DMODEL);
  }

  cls_out_kernel<<<NGLOB, 128, 0, stream>>>(h, out_w, out_b, (float*)d_out);
}

// Round 2
// 12588.905 us; speedup vs baseline: 3.4449x; 3.4449x over previous
//
#include <hip/hip_runtime.h>
#include <cstddef>

#define S_LEN   4096
#define DMODEL  768
#define NHEAD   12
#define DHEAD   64
#define FDIM    3072
#define NLAYER  12
#define WIN     256
#define NGLOB   8
#define GSTRIDE 512

typedef short bf16x8 __attribute__((ext_vector_type(8)));
typedef float f32x4 __attribute__((ext_vector_type(4)));
typedef unsigned short u16;

__device__ __forceinline__ u16 f2bf(float f) {
  unsigned u = __builtin_bit_cast(unsigned, f);
  return (u16)((u + 0x7FFFu + ((u >> 16) & 1u)) >> 16);
}
__device__ __forceinline__ float bf2f(u16 s) {
  unsigned u = ((unsigned)s) << 16;
  return __builtin_bit_cast(float, u);
}

__device__ __forceinline__ float wave_sum(float v) {
#pragma unroll
  for (int off = 32; off > 0; off >>= 1) v += __shfl_xor(v, off);
  return v;
}

__device__ __forceinline__ float block_sum256(float v, float* sbuf) {
  v = wave_sum(v);
  int w = threadIdx.x >> 6;
  __syncthreads();
  if ((threadIdx.x & 63) == 0) sbuf[w] = v;
  __syncthreads();
  return sbuf[0] + sbuf[1] + sbuf[2] + sbuf[3];
}

// ---------------- embedding + LN ----------------
__global__ __launch_bounds__(256) void embed_ln_kernel(
    const int* __restrict__ x, const float* __restrict__ wemb,
    const float* __restrict__ pemb, const float* __restrict__ gg,
    const float* __restrict__ bb, float* __restrict__ h) {
  __shared__ float sbuf[4];
  int s = blockIdx.x, tid = threadIdx.x;
  int idx = x[s];
  float vals[3];
#pragma unroll
  for (int i = 0; i < 3; i++) {
    int d = tid + i * 256;
    vals[i] = wemb[(size_t)idx * DMODEL + d] + pemb[(size_t)s * DMODEL + d];
  }
  float mean = block_sum256(vals[0] + vals[1] + vals[2], sbuf) * (1.0f / 768.0f);
  float sq = 0.f;
#pragma unroll
  for (int i = 0; i < 3; i++) { float t = vals[i] - mean; sq += t * t; }
  float inv = rsqrtf(block_sum256(sq, sbuf) * (1.0f / 768.0f) + 1e-5f);
#pragma unroll
  for (int i = 0; i < 3; i++) {
    int d = tid + i * 256;
    h[(size_t)s * DMODEL + d] = (vals[i] - mean) * inv * gg[d] + bb[d];
  }
}

// ---------------- residual + LN (in place on h) ----------------
__global__ __launch_bounds__(256) void add_ln_kernel(
    float* __restrict__ h, const float* __restrict__ r,
    const float* __restrict__ gg, const float* __restrict__ bb) {
  __shared__ float sbuf[4];
  int s = blockIdx.x, tid = threadIdx.x;
  float vals[3];
#pragma unroll
  for (int i = 0; i < 3; i++) {
    int d = tid + i * 256;
    vals[i] = h[(size_t)s * DMODEL + d] + r[(size_t)s * DMODEL + d];
  }
  float mean = block_sum256(vals[0] + vals[1] + vals[2], sbuf) * (1.0f / 768.0f);
  float sq = 0.f;
#pragma unroll
  for (int i = 0; i < 3; i++) { float t = vals[i] - mean; sq += t * t; }
  float inv = rsqrtf(block_sum256(sq, sbuf) * (1.0f / 768.0f) + 1e-5f);
#pragma unroll
  for (int i = 0; i < 3; i++) {
    int d = tid + i * 256;
    h[(size_t)s * DMODEL + d] = (vals[i] - mean) * inv * gg[d] + bb[d];
  }
}

// ---------------- bf16 MFMA GEMM core ----------------
// C[M,N] = A[M,K]@W[K,N] + bias.  128x128 tile, BK=64, 4 waves (2x2), 16x16x32 MFMA.
// LDS: As[row][g-granule swz], Bs[col][k-granule swz]; swizzle g' = g ^ (row&7).
__device__ __forceinline__ bf16x8 ldg8(const float* p) {
  float4 x = *(const float4*)p;
  float4 y = *(const float4*)(p + 4);
  bf16x8 r;
  r[0] = (short)f2bf(x.x); r[1] = (short)f2bf(x.y); r[2] = (short)f2bf(x.z); r[3] = (short)f2bf(x.w);
  r[4] = (short)f2bf(y.x); r[5] = (short)f2bf(y.y); r[6] = (short)f2bf(y.z); r[7] = (short)f2bf(y.w);
  return r;
}
__device__ __forceinline__ bf16x8 ldg8(const u16* p) { return *(const bf16x8*)p; }

template <int ACT, int OUTM, typename AT>   // OUTM: 0=f32 rm, 1=bf16 rm, 2=bf16 transposed [N][M]
__device__ __forceinline__ void mm_core(const AT* __restrict__ A, const float* __restrict__ W,
                                        const float* __restrict__ bias, void* __restrict__ Cv,
                                        int M, int N, int K, int bm, int bn,
                                        u16* As, u16* Bs) {
  int t = threadIdx.x;
  int wid = t >> 6, lane = t & 63;
  int wr = (wid >> 1) * 64, wc = (wid & 1) * 64;
  int lr = lane & 15, lg = lane >> 4;
  int arow = t >> 1, ag0 = (t & 1) * 4;
  int bcol = t & 127, bk0 = (t >> 7) * 4;
  f32x4 acc[4][4];
  f32x4 zf = {0.f, 0.f, 0.f, 0.f};
#pragma unroll
  for (int m = 0; m < 4; m++)
#pragma unroll
    for (int n = 0; n < 4; n++) acc[m][n] = zf;

  for (int kt = 0; kt < K; kt += 64) {
    bf16x8 av[4], bv[4];
    const AT* ap = A + (size_t)(bm + arow) * K + kt + ag0 * 8;
#pragma unroll
    for (int i = 0; i < 4; i++) av[i] = ldg8(ap + i * 8);
    const float* wp0 = W + (size_t)kt * N + bn + bcol;
#pragma unroll
    for (int i = 0; i < 4; i++) {
      const float* wp = wp0 + (size_t)(bk0 + i) * 8 * N;
      bf16x8 r;
#pragma unroll
      for (int j = 0; j < 8; j++) r[j] = (short)f2bf(wp[(size_t)j * N]);
      bv[i] = r;
    }
    __syncthreads();
#pragma unroll
    for (int i = 0; i < 4; i++)
      *(bf16x8*)&As[arow * 64 + (((ag0 + i) ^ (arow & 7)) * 8)] = av[i];
#pragma unroll
    for (int i = 0; i < 4; i++)
      *(bf16x8*)&Bs[bcol * 64 + (((bk0 + i) ^ (bcol & 7)) * 8)] = bv[i];
    __syncthreads();
#pragma unroll
    for (int ks = 0; ks < 2; ks++) {
      bf16x8 af[4], bfr[4];
#pragma unroll
      for (int m = 0; m < 4; m++)
        af[m] = *(const bf16x8*)&As[(wr + m * 16 + lr) * 64 + (((ks * 4 + lg) ^ (lr & 7)) * 8)];
#pragma unroll
      for (int n = 0; n < 4; n++)
        bfr[n] = *(const bf16x8*)&Bs[(wc + n * 16 + lr) * 64 + (((ks * 4 + lg) ^ (lr & 7)) * 8)];
#pragma unroll
      for (int m = 0; m < 4; m++)
#pragma unroll
        for (int n = 0; n < 4; n++)
          acc[m][n] = __builtin_amdgcn_mfma_f32_16x16x32_bf16(af[m], bfr[n], acc[m][n], 0, 0, 0);
    }
  }
#pragma unroll
  for (int n = 0; n < 4; n++) {
    int col = bn + wc + n * 16 + lr;
    float bb = bias[col];
#pragma unroll
    for (int m = 0; m < 4; m++) {
#pragma unroll
      for (int r = 0; r < 4; r++) {
        int row = bm + wr + m * 16 + lg * 4 + r;
        float xv = acc[m][n][r] + bb;
        if (ACT == 1) xv = 0.5f * xv * (1.0f + erff(xv * 0.70710678118654752f));
        if (OUTM == 0) ((float*)Cv)[(size_t)row * N + col] = xv;
        else if (OUTM == 1) ((u16*)Cv)[(size_t)row * N + col] = f2bf(xv);
        else ((u16*)Cv)[(size_t)col * M + row] = f2bf(xv);
      }
    }
  }
}

template <int ACT, int OUTM, typename AT>
__global__ __launch_bounds__(256) void mm_kernel(const AT* A, const float* W, const float* bias,
                                                 void* Cv, int M, int N, int K) {
  __shared__ u16 As[128 * 64];
  __shared__ u16 Bs[128 * 64];
  mm_core<ACT, OUTM, AT>(A, W, bias, Cv, M, N, K, blockIdx.y * 128, blockIdx.x * 128, As, Bs);
}

// fused q/k/v/kg/vg projections (share A=h).  grid.x = 5*6; slot 2 (v) stores transposed.
__global__ __launch_bounds__(256) void mm5_kernel(
    const float* A,
    const float* W0, const float* W1, const float* W2, const float* W3, const float* W4,
    const float* b0, const float* b1, const float* b2, const float* b3, const float* b4,
    u16* C0, u16* C1, u16* C2, u16* C3, u16* C4, int M, int K) {
  __shared__ u16 As[128 * 64];
  __shared__ u16 Bs[128 * 64];
  int which = blockIdx.x / 6;
  int bn = (blockIdx.x % 6) * 128;
  const float* Ws[5] = {W0, W1, W2, W3, W4};
  const float* bs[5] = {b0, b1, b2, b3, b4};
  u16* Cs[5] = {C0, C1, C2, C3, C4};
  if (which == 2)
    mm_core<0, 2, float>(A, Ws[2], bs[2], Cs[2], M, DMODEL, K, blockIdx.y * 128, bn, As, Bs);
  else
    mm_core<0, 1, float>(A, Ws[which], bs[which], Cs[which], M, DMODEL, K, blockIdx.y * 128, bn, As, Bs);
}

// ---------------- qg projection (fp32, tiny) ----------------
__global__ __launch_bounds__(256) void qg_proj_kernel(
    const float* __restrict__ h, const float* __restrict__ Wqg,
    const float* __restrict__ bqg, float* __restrict__ qg) {
  __shared__ float hs[DMODEL];
  int gi = blockIdx.x;
  const float* hrow = h + (size_t)gi * GSTRIDE * DMODEL;
  int tid = threadIdx.x;
  for (int i = tid; i < DMODEL; i += 256) hs[i] = hrow[i];
  __syncthreads();
  float a0 = bqg[tid], a1 = bqg[tid + 256], a2 = bqg[tid + 512];
  for (int kk = 0; kk < DMODEL; kk++) {
    float hv = hs[kk];
    a0 += hv * Wqg[(size_t)kk * DMODEL + tid];
    a1 += hv * Wqg[(size_t)kk * DMODEL + tid + 256];
    a2 += hv * Wqg[(size_t)kk * DMODEL + tid + 512];
  }
  qg[gi * DMODEL + tid] = a0;
  qg[gi * DMODEL + tid + 256] = a1;
  qg[gi * DMODEL + tid + 512] = a2;
}

// ---------------- gather global-key columns of Vt, zero-padded to 32 ----------------
__global__ __launch_bounds__(256) void vtg_kernel(const u16* __restrict__ vt, u16* __restrict__ vtg) {
  int tid = blockIdx.x * 256 + threadIdx.x;   // 768*32
  int d = tid >> 5, j = tid & 31;
  vtg[tid] = (j < NGLOB) ? vt[(size_t)d * S_LEN + j * GSTRIDE] : (u16)0;
}

// ---------------- sliding-window flash attention (MFMA) ----------------
// block = (head, 64-query tile); wave w owns 16 queries. Tiles: 1 global-key tile + 9 band tiles.
// Q,K frags direct from global bf16; V via transposed Vt; P via swizzled LDS.
__global__ __launch_bounds__(256) void sliding_attn_kernel(
    const u16* __restrict__ qb, const u16* __restrict__ kb,
    const u16* __restrict__ vt, const u16* __restrict__ vtg,
    const int* __restrict__ xmask, u16* __restrict__ ctx) {
  __shared__ u16 Ps[4 * 16 * 64];
  int hh = blockIdx.x >> 6;
  int q0 = (blockIdx.x & 63) * 64;
  int w = threadIdx.x >> 6, lane = threadIdx.x & 63;
  int lr = lane & 15, lg = lane >> 4;
  f32x4 zf = {0.f, 0.f, 0.f, 0.f};

  const u16* qptr = qb + (size_t)(q0 + w * 16 + lr) * DMODEL + hh * DHEAD;
  bf16x8 qf0 = *(const bf16x8*)(qptr + lg * 8);
  bf16x8 qf1 = *(const bf16x8*)(qptr + 32 + lg * 8);

  float m_run[4] = {-1e30f, -1e30f, -1e30f, -1e30f};
  float l_run[4] = {0.f, 0.f, 0.f, 0.f};
  f32x4 ctxa[4] = {zf, zf, zf, zf};

  // ---- global-key tile (8 keys, cols 0..15 real, 16..31 zero-padded for PV) ----
  {
    int krow = (lr < NGLOB) ? lr * GSTRIDE : 0;
    const u16* kp = kb + (size_t)krow * DMODEL + hh * DHEAD + lg * 8;
    f32x4 sa = __builtin_amdgcn_mfma_f32_16x16x32_bf16(qf0, *(const bf16x8*)kp, zf, 0, 0, 0);
    sa = __builtin_amdgcn_mfma_f32_16x16x32_bf16(qf1, *(const bf16x8*)(kp + 32), sa, 0, 0, 0);
    float p0[4], tmax[4];
#pragma unroll
    for (int r = 0; r < 4; r++) {
      float s = (lr < NGLOB) ? sa[r] * 0.125f : -1e30f;
      p0[r] = s; tmax[r] = s;
    }
#pragma unroll
    for (int o = 8; o; o >>= 1)
#pragma unroll
      for (int r = 0; r < 4; r++) tmax[r] = fmaxf(tmax[r], __shfl_xor(tmax[r], o));
    float tsum[4];
#pragma unroll
    for (int r = 0; r < 4; r++) {
      float mn = fmaxf(m_run[r], tmax[r]);
      m_run[r] = mn;
      p0[r] = __expf(p0[r] - mn);
      tsum[r] = p0[r];
    }
#pragma unroll
    for (int o = 8; o; o >>= 1)
#pragma unroll
      for (int r = 0; r < 4; r++) tsum[r] += __shfl_xor(tsum[r], o);
#pragma unroll
    for (int r = 0; r < 4; r++) l_run[r] = tsum[r];
#pragma unroll
    for (int r = 0; r < 4; r++) {
      int qi = lg * 4 + r;
      Ps[w * 1024 + qi * 64 + (((lr >> 3) ^ (qi & 7)) * 8) + (lr & 7)] = f2bf(p0[r]);
      int k2 = 16 + lr;
      Ps[w * 1024 + qi * 64 + (((k2 >> 3) ^ (qi & 7)) * 8) + (k2 & 7)] = 0;
    }
    bf16x8 pf = *(const bf16x8*)&Ps[w * 1024 + lr * 64 + ((lg ^ (lr & 7)) * 8)];
#pragma unroll
    for (int c2 = 0; c2 < 4; c2++) {
      const u16* vp = vtg + (size_t)(hh * DHEAD + c2 * 16 + lr) * 32 + lg * 8;
      ctxa[c2] = __builtin_amdgcn_mfma_f32_16x16x32_bf16(pf, *(const bf16x8*)vp, ctxa[c2], 0, 0, 0);
    }
  }

  // ---- 9 band tiles of 64 keys ----
  for (int tt = 0; tt < 9; tt++) {
    int base = q0 - WIN + tt * 64;
    if (base + 63 < 0 || base >= S_LEN) continue;
    f32x4 sa[4];
    int keyc[4]; bool vc[4];
#pragma unroll
    for (int c = 0; c < 4; c++) {
      int key = base + c * 16 + lr;
      int krow = key < 0 ? 0 : (key > S_LEN - 1 ? S_LEN - 1 : key);
      vc[c] = (key >= 0) && (key < S_LEN) && ((key & (GSTRIDE - 1)) != 0) && (xmask[krow] != 0);
      keyc[c] = key;
      const u16* kp = kb + (size_t)krow * DMODEL + hh * DHEAD + lg * 8;
      sa[c] = __builtin_amdgcn_mfma_f32_16x16x32_bf16(qf0, *(const bf16x8*)kp, zf, 0, 0, 0);
      sa[c] = __builtin_amdgcn_mfma_f32_16x16x32_bf16(qf1, *(const bf16x8*)(kp + 32), sa[c], 0, 0, 0);
    }
    float p[4][4], tmax[4] = {-1e30f, -1e30f, -1e30f, -1e30f};
#pragma unroll
    for (int c = 0; c < 4; c++)
#pragma unroll
      for (int r = 0; r < 4; r++) {
        int qrow = q0 + w * 16 + lg * 4 + r;
        int dd = keyc[c] - qrow;
        float s = (vc[c] && dd >= -WIN && dd <= WIN) ? sa[c][r] * 0.125f : -1e30f;
        p[c][r] = s;
        tmax[r] = fmaxf(tmax[r], s);
      }
#pragma unroll
    for (int o = 8; o; o >>= 1)
#pragma unroll
      for (int r = 0; r < 4; r++) tmax[r] = fmaxf(tmax[r], __shfl_xor(tmax[r], o));
    float sc[4], tsum[4] = {0.f, 0.f, 0.f, 0.f};
#pragma unroll
    for (int r = 0; r < 4; r++) {
      float mn = fmaxf(m_run[r], tmax[r]);
      sc[r] = __expf(m_run[r] - mn);
      m_run[r] = mn;
    }
#pragma unroll
    for (int c = 0; c < 4; c++)
#pragma unroll
      for (int r = 0; r < 4; r++) {
        p[c][r] = __expf(p[c][r] - m_run[r]);
        tsum[r] += p[c][r];
      }
#pragma unroll
    for (int o = 8; o; o >>= 1)
#pragma unroll
      for (int r = 0; r < 4; r++) tsum[r] += __shfl_xor(tsum[r], o);
#pragma unroll
    for (int r = 0; r < 4; r++) l_run[r] = l_run[r] * sc[r] + tsum[r];
#pragma unroll
    for (int c2 = 0; c2 < 4; c2++)
#pragma unroll
      for (int r = 0; r < 4; r++) ctxa[c2][r] *= sc[r];
#pragma unroll
    for (int c = 0; c < 4; c++)
#pragma unroll
      for (int r = 0; r < 4; r++) {
        int qi = lg * 4 + r, k64 = c * 16 + lr;
        Ps[w * 1024 + qi * 64 + (((k64 >> 3) ^ (qi & 7)) * 8) + (k64 & 7)] = f2bf(p[c][r]);
      }
#pragma unroll
    for (int ks = 0; ks < 2; ks++) {
      bf16x8 pf = *(const bf16x8*)&Ps[w * 1024 + lr * 64 + (((ks * 4 + lg) ^ (lr & 7)) * 8)];
      int kstart = base + ks * 32 + lg * 8;
      int kc = kstart < 0 ? 0 : (kstart > S_LEN - 8 ? S_LEN - 8 : kstart);
#pragma unroll
      for (int c2 = 0; c2 < 4; c2++) {
        const u16* vp = vt + (size_t)(hh * DHEAD + c2 * 16 + lr) * S_LEN + kc;
        ctxa[c2] = __builtin_amdgcn_mfma_f32_16x16x32_bf16(pf, *(const bf16x8*)vp, ctxa[c2], 0, 0, 0);
      }
    }
  }

#pragma unroll
  for (int c2 = 0; c2 < 4; c2++)
#pragma unroll
    for (int r = 0; r < 4; r++) {
      int qrow = q0 + w * 16 + lg * 4 + r;
      ctx[(size_t)qrow * DMODEL + hh * DHEAD + c2 * 16 + lr] = f2bf(ctxa[c2][r] / l_run[r]);
    }
}

// ---------------- global-token attention (8 queries, wave-serial, bf16 K/V) ------
__global__ __launch_bounds__(256) void global_attn_kernel(
    const float* __restrict__ qg, const u16* __restrict__ kg,
    const u16* __restrict__ vg, const int* __restrict__ xmask,
    u16* __restrict__ ctx) {
  __shared__ float sm[4], sl[4], sacc[4][64];
  int gi = blockIdx.x / NHEAD, hh = blockIdx.x % NHEAD;
  int w = threadIdx.x >> 6, lane = threadIdx.x & 63;
  int col = hh * DHEAD + lane;
  float qv = qg[gi * DMODEL + col] * 0.125f;
  float m = -1e30f, l = 0.f, acc = 0.f;
  for (int s = w * (S_LEN / 4); s < (w + 1) * (S_LEN / 4); s++) {
    bool ok = (xmask[s] != 0) || ((s & (GSTRIDE - 1)) == 0);
    if (!ok) continue;
    float d = wave_sum(qv * bf2f(kg[(size_t)s * DMODEL + col]));
    float vv = bf2f(vg[(size_t)s * DMODEL + col]);
    float mn = fmaxf(m, d);
    float p = __expf(d - mn);
    float al = __expf(m - mn);
    l = l * al + p;
    acc = acc * al + p * vv;
    m = mn;
  }
  if (lane == 0) { sm[w] = m; sl[w] = l; }
  sacc[w][lane] = acc;
  __syncthreads();
  if (w == 0) {
    float M = fmaxf(fmaxf(sm[0], sm[1]), fmaxf(sm[2], sm[3]));
    float L = 0.f, A = 0.f;
#pragma unroll
    for (int j = 0; j < 4; j++) {
      float al = __expf(sm[j] - M);
      L += sl[j] * al;
      A += sacc[j][lane] * al;
    }
    ctx[(size_t)gi * GSTRIDE * DMODEL + col] = f2bf(A / L);
  }
}

// ---------------- CLS pooling + output projection -----------------
__global__ __launch_bounds__(128) void cls_out_kernel(
    const float* __restrict__ h, const float* __restrict__ ow,
    const float* __restrict__ ob, float* __restrict__ y) {
  __shared__ float hs[DMODEL];
  int wi = blockIdx.x;
  int tid = threadIdx.x;
  for (int i = tid; i < DMODEL; i += 128) hs[i] = h[(size_t)wi * GSTRIDE * DMODEL + i];
  __syncthreads();
  float a = ob[tid];
  for (int d = 0; d < DMODEL; d++) a += hs[d] * ow[d * 128 + tid];
  y[wi * 128 + tid] = a;
}

// ---------------- host launch ----------------
extern "C" void kernel_launch(void* const* d_in, const int* in_sizes, int n_in,
                              void* d_out, int out_size, void* d_ws, size_t ws_size,
                              hipStream_t stream) {
  const int*   x      = (const int*)d_in[0];
  const int*   xmask  = (const int*)d_in[1];
  const float* wemb   = (const float*)d_in[2];
  const float* pemb   = (const float*)d_in[3];
  const float* emb_g  = (const float*)d_in[4];
  const float* emb_b  = (const float*)d_in[5];
  const float* Wq     = (const float*)d_in[6];
  const float* bq     = (const float*)d_in[7];
  const float* Wk     = (const float*)d_in[8];
  const float* bk     = (const float*)d_in[9];
  const float* Wv     = (const float*)d_in[10];
  const float* bv     = (const float*)d_in[11];
  const float* Wo     = (const float*)d_in[12];
  const float* bo     = (const float*)d_in[13];
  const float* Wqg    = (const float*)d_in[14];
  const float* bqg    = (const float*)d_in[15];
  const float* Wkg    = (const float*)d_in[16];
  const float* bkg    = (const float*)d_in[17];
  const float* Wvg    = (const float*)d_in[18];
  const float* bvg    = (const float*)d_in[19];
  const float* ln1_g  = (const float*)d_in[20];
  const float* ln1_b  = (const float*)d_in[21];
  const float* W1     = (const float*)d_in[22];
  const float* b1     = (const float*)d_in[23];
  const float* W2     = (const float*)d_in[24];
  const float* b2     = (const float*)d_in[25];
  const float* ln2_g  = (const float*)d_in[26];
  const float* ln2_b  = (const float*)d_in[27];
  const float* out_w  = (const float*)d_in[28];
  const float* out_b  = (const float*)d_in[29];

  char* wsp = (char*)d_ws;
  float* h   = (float*)wsp;  wsp += (size_t)S_LEN * DMODEL * 4;
  float* tmp = (float*)wsp;  wsp += (size_t)S_LEN * DMODEL * 4;
  u16* ctx = (u16*)wsp;      wsp += (size_t)S_LEN * DMODEL * 2;
  u16* qb  = (u16*)wsp;      wsp += (size_t)S_LEN * DMODEL * 2;
  u16* kb  = (u16*)wsp;      wsp += (size_t)S_LEN * DMODEL * 2;
  u16* vt  = (u16*)wsp;      wsp += (size_t)S_LEN * DMODEL * 2;
  u16* kgb = (u16*)wsp;      wsp += (size_t)S_LEN * DMODEL * 2;
  u16* vgb = (u16*)wsp;      wsp += (size_t)S_LEN * DMODEL * 2;
  u16* mid = (u16*)wsp;      wsp += (size_t)S_LEN * FDIM * 2;
  float* qgb = (float*)wsp;  wsp += (size_t)NGLOB * DMODEL * 4;
  u16* vtg = (u16*)wsp;      wsp += (size_t)DMODEL * 32 * 2;

  embed_ln_kernel<<<S_LEN, 256, 0, stream>>>(x, wemb, pemb, emb_g, emb_b, h);

  const size_t DD = (size_t)DMODEL * DMODEL;
  const size_t DF = (size_t)DMODEL * FDIM;

  for (int l = 0; l < NLAYER; l++) {
    const float* wq  = Wq  + (size_t)l * DD;  const float* bql  = bq  + (size_t)l * DMODEL;
    const float* wk  = Wk  + (size_t)l * DD;  const float* bkl  = bk  + (size_t)l * DMODEL;
    const float* wv  = Wv  + (size_t)l * DD;  const float* bvl  = bv  + (size_t)l * DMODEL;
    const float* wo  = Wo  + (size_t)l * DD;  const float* bol  = bo  + (size_t)l * DMODEL;
    const float* wqg = Wqg + (size_t)l * DD;  const float* bqgl = bqg + (size_t)l * DMODEL;
    const float* wkg = Wkg + (size_t)l * DD;  const float* bkgl = bkg + (size_t)l * DMODEL;
    const float* wvg = Wvg + (size_t)l * DD;  const float* bvgl = bvg + (size_t)l * DMODEL;
    const float* w1  = W1  + (size_t)l * DF;  const float* b1l  = b1  + (size_t)l * FDIM;
    const float* w2  = W2  + (size_t)l * DF;  const float* b2l  = b2  + (size_t)l * DMODEL;

    mm5_kernel<<<dim3(30, 32), 256, 0, stream>>>(
        h, wq, wk, wv, wkg, wvg, bql, bkl, bvl, bkgl, bvgl,
        qb, kb, vt, kgb, vgb, S_LEN, DMODEL);
    qg_proj_kernel<<<NGLOB, 256, 0, stream>>>(h, wqg, bqgl, qgb);
    vtg_kernel<<<(DMODEL * 32) / 256, 256, 0, stream>>>(vt, vtg);

    sliding_attn_kernel<<<NHEAD * 64, 256, 0, stream>>>(qb, kb, vt, vtg, xmask, ctx);
    global_attn_kernel<<<NGLOB * NHEAD, 256, 0, stream>>>(qgb, kgb, vgb, xmask, ctx);

    mm_kernel<0, 0, u16><<<dim3(6, 32), 256, 0, stream>>>(ctx, wo, bol, tmp, S_LEN, DMODEL, DMODEL);
    add_ln_kernel<<<S_LEN, 256, 0, stream>>>(h, tmp, ln1_g + (size_t)l * DMODEL, ln1_b + (size_t)l * DMODEL);

    mm_kernel<1, 1, float><<<dim3(24, 32), 256, 0, stream>>>(h, w1, b1l, mid, S_LEN, FDIM, DMODEL);
    mm_kernel<0, 0, u16><<<dim3(6, 32), 256, 0, stream>>>(mid, w2, b2l, tmp, S_LEN, DMODEL, FDIM);
    add_ln_kernel<<<S_LEN, 256, 0, stream>>>(h, tmp, ln2_g + (size_t)l * DMODEL, ln2_b + (size_t)l * DMODEL);
  }

  cls_out_kernel<<<NGLOB, 128, 0, stream>>>(h, out_w, out_b, (float*)d_out);
}

// Round 3
// 5439.209 us; speedup vs baseline: 7.9732x; 2.3145x over previous
//
#include <hip/hip_runtime.h>
#include <cstddef>

#define S_LEN   4096
#define DMODEL  768
#define NHEAD   12
#define DHEAD   64
#define FDIM    3072
#define NLAYER  12
#define WIN     256
#define NGLOB   8
#define GSTRIDE 512

typedef short bf16x8 __attribute__((ext_vector_type(8)));
typedef float f32x4 __attribute__((ext_vector_type(4)));
typedef unsigned short u16;

__device__ __forceinline__ u16 f2bf(float f) {
  unsigned u = __builtin_bit_cast(unsigned, f);
  return (u16)((u + 0x7FFFu + ((u >> 16) & 1u)) >> 16);
}
__device__ __forceinline__ float bf2f(u16 s) {
  unsigned u = ((unsigned)s) << 16;
  return __builtin_bit_cast(float, u);
}

__device__ __forceinline__ float wave_sum(float v) {
#pragma unroll
  for (int off = 32; off > 0; off >>= 1) v += __shfl_xor(v, off);
  return v;
}

__device__ __forceinline__ float block_sum256(float v, float* sbuf) {
  v = wave_sum(v);
  int w = threadIdx.x >> 6;
  __syncthreads();
  if ((threadIdx.x & 63) == 0) sbuf[w] = v;
  __syncthreads();
  return sbuf[0] + sbuf[1] + sbuf[2] + sbuf[3];
}

// ---------------- embedding + LN ----------------
__global__ __launch_bounds__(256) void embed_ln_kernel(
    const int* __restrict__ x, const float* __restrict__ wemb,
    const float* __restrict__ pemb, const float* __restrict__ gg,
    const float* __restrict__ bb, float* __restrict__ h) {
  __shared__ float sbuf[4];
  int s = blockIdx.x, tid = threadIdx.x;
  int idx = x[s];
  float vals[3];
#pragma unroll
  for (int i = 0; i < 3; i++) {
    int d = tid + i * 256;
    vals[i] = wemb[(size_t)idx * DMODEL + d] + pemb[(size_t)s * DMODEL + d];
  }
  float mean = block_sum256(vals[0] + vals[1] + vals[2], sbuf) * (1.0f / 768.0f);
  float sq = 0.f;
#pragma unroll
  for (int i = 0; i < 3; i++) { float t = vals[i] - mean; sq += t * t; }
  float inv = rsqrtf(block_sum256(sq, sbuf) * (1.0f / 768.0f) + 1e-5f);
#pragma unroll
  for (int i = 0; i < 3; i++) {
    int d = tid + i * 256;
    h[(size_t)s * DMODEL + d] = (vals[i] - mean) * inv * gg[d] + bb[d];
  }
}

// ---------------- residual + LN (in place on h) ----------------
__global__ __launch_bounds__(256) void add_ln_kernel(
    float* __restrict__ h, const float* __restrict__ r,
    const float* __restrict__ gg, const float* __restrict__ bb) {
  __shared__ float sbuf[4];
  int s = blockIdx.x, tid = threadIdx.x;
  float vals[3];
#pragma unroll
  for (int i = 0; i < 3; i++) {
    int d = tid + i * 256;
    vals[i] = h[(size_t)s * DMODEL + d] + r[(size_t)s * DMODEL + d];
  }
  float mean = block_sum256(vals[0] + vals[1] + vals[2], sbuf) * (1.0f / 768.0f);
  float sq = 0.f;
#pragma unroll
  for (int i = 0; i < 3; i++) { float t = vals[i] - mean; sq += t * t; }
  float inv = rsqrtf(block_sum256(sq, sbuf) * (1.0f / 768.0f) + 1e-5f);
#pragma unroll
  for (int i = 0; i < 3; i++) {
    int d = tid + i * 256;
    h[(size_t)s * DMODEL + d] = (vals[i] - mean) * inv * gg[d] + bb[d];
  }
}

// ---------------- bf16 MFMA GEMM core ----------------
__device__ __forceinline__ bf16x8 ldg8(const float* p) {
  float4 x = *(const float4*)p;
  float4 y = *(const float4*)(p + 4);
  bf16x8 r;
  r[0] = (short)f2bf(x.x); r[1] = (short)f2bf(x.y); r[2] = (short)f2bf(x.z); r[3] = (short)f2bf(x.w);
  r[4] = (short)f2bf(y.x); r[5] = (short)f2bf(y.y); r[6] = (short)f2bf(y.z); r[7] = (short)f2bf(y.w);
  return r;
}
__device__ __forceinline__ bf16x8 ldg8(const u16* p) { return *(const bf16x8*)p; }

template <int ACT, int OUTM, typename AT>   // OUTM: 0=f32 rm, 1=bf16 rm, 2=bf16 transposed [N][M]
__device__ __forceinline__ void mm_core(const AT* __restrict__ A, const float* __restrict__ W,
                                        const float* __restrict__ bias, void* __restrict__ Cv,
                                        int M, int N, int K, int bm, int bn,
                                        u16* As, u16* Bs) {
  int t = threadIdx.x;
  int wid = t >> 6, lane = t & 63;
  int wr = (wid >> 1) * 64, wc = (wid & 1) * 64;
  int lr = lane & 15, lg = lane >> 4;
  int arow = t >> 1, ag0 = (t & 1) * 4;
  int bcol = t & 127, bk0 = (t >> 7) * 4;
  f32x4 acc[4][4];
  f32x4 zf = {0.f, 0.f, 0.f, 0.f};
#pragma unroll
  for (int m = 0; m < 4; m++)
#pragma unroll
    for (int n = 0; n < 4; n++) acc[m][n] = zf;

  for (int kt = 0; kt < K; kt += 64) {
    bf16x8 av[4], bv[4];
    const AT* ap = A + (size_t)(bm + arow) * K + kt + ag0 * 8;
#pragma unroll
    for (int i = 0; i < 4; i++) av[i] = ldg8(ap + i * 8);
    const float* wp0 = W + (size_t)kt * N + bn + bcol;
#pragma unroll
    for (int i = 0; i < 4; i++) {
      const float* wp = wp0 + (size_t)(bk0 + i) * 8 * N;
      bf16x8 r;
#pragma unroll
      for (int j = 0; j < 8; j++) r[j] = (short)f2bf(wp[(size_t)j * N]);
      bv[i] = r;
    }
    __syncthreads();
#pragma unroll
    for (int i = 0; i < 4; i++)
      *(bf16x8*)&As[arow * 64 + (((ag0 + i) ^ (arow & 7)) * 8)] = av[i];
#pragma unroll
    for (int i = 0; i < 4; i++)
      *(bf16x8*)&Bs[bcol * 64 + (((bk0 + i) ^ (bcol & 7)) * 8)] = bv[i];
    __syncthreads();
#pragma unroll
    for (int ks = 0; ks < 2; ks++) {
      bf16x8 af[4], bfr[4];
#pragma unroll
      for (int m = 0; m < 4; m++)
        af[m] = *(const bf16x8*)&As[(wr + m * 16 + lr) * 64 + (((ks * 4 + lg) ^ (lr & 7)) * 8)];
#pragma unroll
      for (int n = 0; n < 4; n++)
        bfr[n] = *(const bf16x8*)&Bs[(wc + n * 16 + lr) * 64 + (((ks * 4 + lg) ^ (lr & 7)) * 8)];
#pragma unroll
      for (int m = 0; m < 4; m++)
#pragma unroll
        for (int n = 0; n < 4; n++)
          acc[m][n] = __builtin_amdgcn_mfma_f32_16x16x32_bf16(af[m], bfr[n], acc[m][n], 0, 0, 0);
    }
  }
#pragma unroll
  for (int n = 0; n < 4; n++) {
    int col = bn + wc + n * 16 + lr;
    float bb = bias[col];
#pragma unroll
    for (int m = 0; m < 4; m++) {
#pragma unroll
      for (int r = 0; r < 4; r++) {
        int row = bm + wr + m * 16 + lg * 4 + r;
        float xv = acc[m][n][r] + bb;
        if (ACT == 1) xv = 0.5f * xv * (1.0f + erff(xv * 0.70710678118654752f));
        if (OUTM == 0) ((float*)Cv)[(size_t)row * N + col] = xv;
        else if (OUTM == 1) ((u16*)Cv)[(size_t)row * N + col] = f2bf(xv);
        else ((u16*)Cv)[(size_t)col * M + row] = f2bf(xv);
      }
    }
  }
}

template <int ACT, int OUTM, typename AT>
__global__ __launch_bounds__(256) void mm_kernel(const AT* A, const float* W, const float* bias,
                                                 void* Cv, int M, int N, int K) {
  __shared__ u16 As[128 * 64];
  __shared__ u16 Bs[128 * 64];
  mm_core<ACT, OUTM, AT>(A, W, bias, Cv, M, N, K, blockIdx.y * 128, blockIdx.x * 128, As, Bs);
}

// fused q/k/v/kg/vg projections. slots 2 (v) and 4 (vg) store transposed.
__global__ __launch_bounds__(256) void mm5_kernel(
    const float* A,
    const float* W0, const float* W1, const float* W2, const float* W3, const float* W4,
    const float* b0, const float* b1, const float* b2, const float* b3, const float* b4,
    u16* C0, u16* C1, u16* C2, u16* C3, u16* C4, int M, int K) {
  __shared__ u16 As[128 * 64];
  __shared__ u16 Bs[128 * 64];
  int which = blockIdx.x / 6;
  int bn = (blockIdx.x % 6) * 128;
  const float* Ws[5] = {W0, W1, W2, W3, W4};
  const float* bs[5] = {b0, b1, b2, b3, b4};
  u16* Cs[5] = {C0, C1, C2, C3, C4};
  if (which == 2 || which == 4)
    mm_core<0, 2, float>(A, Ws[which], bs[which], Cs[which], M, DMODEL, K, blockIdx.y * 128, bn, As, Bs);
  else
    mm_core<0, 1, float>(A, Ws[which], bs[which], Cs[which], M, DMODEL, K, blockIdx.y * 128, bn, As, Bs);
}

// ---------------- qg projection (fp32, tiny) ----------------
__global__ __launch_bounds__(256) void qg_proj_kernel(
    const float* __restrict__ h, const float* __restrict__ Wqg,
    const float* __restrict__ bqg, float* __restrict__ qg) {
  __shared__ float hs[DMODEL];
  int gi = blockIdx.x;
  const float* hrow = h + (size_t)gi * GSTRIDE * DMODEL;
  int tid = threadIdx.x;
  for (int i = tid; i < DMODEL; i += 256) hs[i] = hrow[i];
  __syncthreads();
  float a0 = bqg[tid], a1 = bqg[tid + 256], a2 = bqg[tid + 512];
  for (int kk = 0; kk < DMODEL; kk++) {
    float hv = hs[kk];
    a0 += hv * Wqg[(size_t)kk * DMODEL + tid];
    a1 += hv * Wqg[(size_t)kk * DMODEL + tid + 256];
    a2 += hv * Wqg[(size_t)kk * DMODEL + tid + 512];
  }
  qg[gi * DMODEL + tid] = a0;
  qg[gi * DMODEL + tid + 256] = a1;
  qg[gi * DMODEL + tid + 512] = a2;
}

// ---------------- gather global-key columns of Vt, zero-padded to 32 ----------------
__global__ __launch_bounds__(256) void vtg_kernel(const u16* __restrict__ vt, u16* __restrict__ vtg) {
  int tid = blockIdx.x * 256 + threadIdx.x;   // 768*32
  int d = tid >> 5, j = tid & 31;
  vtg[tid] = (j < NGLOB) ? vt[(size_t)d * S_LEN + j * GSTRIDE] : (u16)0;
}

// ---------------- sliding-window flash attention (MFMA) ----------------
__global__ __launch_bounds__(256) void sliding_attn_kernel(
    const u16* __restrict__ qb, const u16* __restrict__ kb,
    const u16* __restrict__ vt, const u16* __restrict__ vtg,
    const int* __restrict__ xmask, u16* __restrict__ ctx) {
  __shared__ u16 Ps[4 * 16 * 64];
  int hh = blockIdx.x >> 6;
  int q0 = (blockIdx.x & 63) * 64;
  int w = threadIdx.x >> 6, lane = threadIdx.x & 63;
  int lr = lane & 15, lg = lane >> 4;
  f32x4 zf = {0.f, 0.f, 0.f, 0.f};

  const u16* qptr = qb + (size_t)(q0 + w * 16 + lr) * DMODEL + hh * DHEAD;
  bf16x8 qf0 = *(const bf16x8*)(qptr + lg * 8);
  bf16x8 qf1 = *(const bf16x8*)(qptr + 32 + lg * 8);

  float m_run[4] = {-1e30f, -1e30f, -1e30f, -1e30f};
  float l_run[4] = {0.f, 0.f, 0.f, 0.f};
  f32x4 ctxa[4] = {zf, zf, zf, zf};

  // ---- global-key tile (8 keys, cols 0..15 real, 16..31 zero-padded for PV) ----
  {
    int krow = (lr < NGLOB) ? lr * GSTRIDE : 0;
    const u16* kp = kb + (size_t)krow * DMODEL + hh * DHEAD + lg * 8;
    f32x4 sa = __builtin_amdgcn_mfma_f32_16x16x32_bf16(qf0, *(const bf16x8*)kp, zf, 0, 0, 0);
    sa = __builtin_amdgcn_mfma_f32_16x16x32_bf16(qf1, *(const bf16x8*)(kp + 32), sa, 0, 0, 0);
    float p0[4], tmax[4];
#pragma unroll
    for (int r = 0; r < 4; r++) {
      float s = (lr < NGLOB) ? sa[r] * 0.125f : -1e30f;
      p0[r] = s; tmax[r] = s;
    }
#pragma unroll
    for (int o = 8; o; o >>= 1)
#pragma unroll
      for (int r = 0; r < 4; r++) tmax[r] = fmaxf(tmax[r], __shfl_xor(tmax[r], o));
    float tsum[4];
#pragma unroll
    for (int r = 0; r < 4; r++) {
      float mn = fmaxf(m_run[r], tmax[r]);
      m_run[r] = mn;
      p0[r] = __expf(p0[r] - mn);
      tsum[r] = p0[r];
    }
#pragma unroll
    for (int o = 8; o; o >>= 1)
#pragma unroll
      for (int r = 0; r < 4; r++) tsum[r] += __shfl_xor(tsum[r], o);
#pragma unroll
    for (int r = 0; r < 4; r++) l_run[r] = tsum[r];
#pragma unroll
    for (int r = 0; r < 4; r++) {
      int qi = lg * 4 + r;
      Ps[w * 1024 + qi * 64 + (((lr >> 3) ^ (qi & 7)) * 8) + (lr & 7)] = f2bf(p0[r]);
      int k2 = 16 + lr;
      Ps[w * 1024 + qi * 64 + (((k2 >> 3) ^ (qi & 7)) * 8) + (k2 & 7)] = 0;
    }
    bf16x8 pf = *(const bf16x8*)&Ps[w * 1024 + lr * 64 + ((lg ^ (lr & 7)) * 8)];
#pragma unroll
    for (int c2 = 0; c2 < 4; c2++) {
      const u16* vp = vtg + (size_t)(hh * DHEAD + c2 * 16 + lr) * 32 + lg * 8;
      ctxa[c2] = __builtin_amdgcn_mfma_f32_16x16x32_bf16(pf, *(const bf16x8*)vp, ctxa[c2], 0, 0, 0);
    }
  }

  // ---- 9 band tiles of 64 keys ----
  for (int tt = 0; tt < 9; tt++) {
    int base = q0 - WIN + tt * 64;
    if (base + 63 < 0 || base >= S_LEN) continue;
    f32x4 sa[4];
    int keyc[4]; bool vc[4];
#pragma unroll
    for (int c = 0; c < 4; c++) {
      int key = base + c * 16 + lr;
      int krow = key < 0 ? 0 : (key > S_LEN - 1 ? S_LEN - 1 : key);
      vc[c] = (key >= 0) && (key < S_LEN) && ((key & (GSTRIDE - 1)) != 0) && (xmask[krow] != 0);
      keyc[c] = key;
      const u16* kp = kb + (size_t)krow * DMODEL + hh * DHEAD + lg * 8;
      sa[c] = __builtin_amdgcn_mfma_f32_16x16x32_bf16(qf0, *(const bf16x8*)kp, zf, 0, 0, 0);
      sa[c] = __builtin_amdgcn_mfma_f32_16x16x32_bf16(qf1, *(const bf16x8*)(kp + 32), sa[c], 0, 0, 0);
    }
    float p[4][4], tmax[4] = {-1e30f, -1e30f, -1e30f, -1e30f};
#pragma unroll
    for (int c = 0; c < 4; c++)
#pragma unroll
      for (int r = 0; r < 4; r++) {
        int qrow = q0 + w * 16 + lg * 4 + r;
        int dd = keyc[c] - qrow;
        float s = (vc[c] && dd >= -WIN && dd <= WIN) ? sa[c][r] * 0.125f : -1e30f;
        p[c][r] = s;
        tmax[r] = fmaxf(tmax[r], s);
      }
#pragma unroll
    for (int o = 8; o; o >>= 1)
#pragma unroll
      for (int r = 0; r < 4; r++) tmax[r] = fmaxf(tmax[r], __shfl_xor(tmax[r], o));
    float sc[4], tsum[4] = {0.f, 0.f, 0.f, 0.f};
#pragma unroll
    for (int r = 0; r < 4; r++) {
      float mn = fmaxf(m_run[r], tmax[r]);
      sc[r] = __expf(m_run[r] - mn);
      m_run[r] = mn;
    }
#pragma unroll
    for (int c = 0; c < 4; c++)
#pragma unroll
      for (int r = 0; r < 4; r++) {
        p[c][r] = __expf(p[c][r] - m_run[r]);
        tsum[r] += p[c][r];
      }
#pragma unroll
    for (int o = 8; o; o >>= 1)
#pragma unroll
      for (int r = 0; r < 4; r++) tsum[r] += __shfl_xor(tsum[r], o);
#pragma unroll
    for (int r = 0; r < 4; r++) l_run[r] = l_run[r] * sc[r] + tsum[r];
#pragma unroll
    for (int c2 = 0; c2 < 4; c2++)
#pragma unroll
      for (int r = 0; r < 4; r++) ctxa[c2][r] *= sc[r];
#pragma unroll
    for (int c = 0; c < 4; c++)
#pragma unroll
      for (int r = 0; r < 4; r++) {
        int qi = lg * 4 + r, k64 = c * 16 + lr;
        Ps[w * 1024 + qi * 64 + (((k64 >> 3) ^ (qi & 7)) * 8) + (k64 & 7)] = f2bf(p[c][r]);
      }
#pragma unroll
    for (int ks = 0; ks < 2; ks++) {
      bf16x8 pf = *(const bf16x8*)&Ps[w * 1024 + lr * 64 + (((ks * 4 + lg) ^ (lr & 7)) * 8)];
      int kstart = base + ks * 32 + lg * 8;
      int kc = kstart < 0 ? 0 : (kstart > S_LEN - 8 ? S_LEN - 8 : kstart);
#pragma unroll
      for (int c2 = 0; c2 < 4; c2++) {
        const u16* vp = vt + (size_t)(hh * DHEAD + c2 * 16 + lr) * S_LEN + kc;
        ctxa[c2] = __builtin_amdgcn_mfma_f32_16x16x32_bf16(pf, *(const bf16x8*)vp, ctxa[c2], 0, 0, 0);
      }
    }
  }

#pragma unroll
  for (int c2 = 0; c2 < 4; c2++)
#pragma unroll
    for (int r = 0; r < 4; r++) {
      int qrow = q0 + w * 16 + lg * 4 + r;
      ctx[(size_t)qrow * DMODEL + hh * DHEAD + c2 * 16 + lr] = f2bf(ctxa[c2][r] / l_run[r]);
    }
}

// ---------------- global-token attention, phase 1: per-(head,chunk,wave) partials ----
// grid (NHEAD, 16), 256 thr. Wave w owns 64 keys of its 256-key chunk.
// Partials: pm/pl[pidx][8], pacc[pidx][8][64], pidx = (hh*16+c)*4+w  (768 total).
__global__ __launch_bounds__(256) void gattn_part_kernel(
    const float* __restrict__ qg, const u16* __restrict__ kg,
    const u16* __restrict__ vgt, const int* __restrict__ xmask,
    float* __restrict__ pm, float* __restrict__ pl, float* __restrict__ pacc) {
  __shared__ u16 Ps[4 * 16 * 64];
  int hh = blockIdx.x;
  int c  = blockIdx.y;
  int w = threadIdx.x >> 6, lane = threadIdx.x & 63;
  int lr = lane & 15, lg = lane >> 4;
  int base = c * 256 + w * 64;
  f32x4 zf = {0.f, 0.f, 0.f, 0.f};

  // Q frag: rows 0..7 real (pre-scaled by 1/8 exactly), rows 8..15 zero.
  bf16x8 qf0, qf1;
  {
    const float* qp = qg + (size_t)(lr & 7) * DMODEL + hh * DHEAD;
    bool real = lr < 8;
#pragma unroll
    for (int j = 0; j < 8; j++) {
      qf0[j] = real ? (short)f2bf(0.125f * qp[lg * 8 + j]) : (short)0;
      qf1[j] = real ? (short)f2bf(0.125f * qp[32 + lg * 8 + j]) : (short)0;
    }
  }

  f32x4 sa[4];
  bool vc[4];
#pragma unroll
  for (int st = 0; st < 4; st++) {
    int key = base + st * 16 + lr;
    vc[st] = (xmask[key] != 0) || ((key & (GSTRIDE - 1)) == 0);
    const u16* kp = kg + (size_t)key * DMODEL + hh * DHEAD + lg * 8;
    sa[st] = __builtin_amdgcn_mfma_f32_16x16x32_bf16(qf0, *(const bf16x8*)kp, zf, 0, 0, 0);
    sa[st] = __builtin_amdgcn_mfma_f32_16x16x32_bf16(qf1, *(const bf16x8*)(kp + 32), sa[st], 0, 0, 0);
  }
  float p[4][4], tmax[4] = {-1e30f, -1e30f, -1e30f, -1e30f};
#pragma unroll
  for (int st = 0; st < 4; st++)
#pragma unroll
    for (int r = 0; r < 4; r++) {
      float s = vc[st] ? sa[st][r] : -1e30f;
      p[st][r] = s;
      tmax[r] = fmaxf(tmax[r], s);
    }
#pragma unroll
  for (int o = 8; o; o >>= 1)
#pragma unroll
    for (int r = 0; r < 4; r++) tmax[r] = fmaxf(tmax[r], __shfl_xor(tmax[r], o));
  float tsum[4] = {0.f, 0.f, 0.f, 0.f};
#pragma unroll
  for (int st = 0; st < 4; st++)
#pragma unroll
    for (int r = 0; r < 4; r++) {
      float pv = vc[st] ? __expf(p[st][r] - tmax[r]) : 0.f;
      p[st][r] = pv;
      tsum[r] += pv;
    }
#pragma unroll
  for (int o = 8; o; o >>= 1)
#pragma unroll
    for (int r = 0; r < 4; r++) tsum[r] += __shfl_xor(tsum[r], o);
#pragma unroll
  for (int st = 0; st < 4; st++)
#pragma unroll
    for (int r = 0; r < 4; r++) {
      int qi = lg * 4 + r, k64 = st * 16 + lr;
      Ps[w * 1024 + qi * 64 + (((k64 >> 3) ^ (qi & 7)) * 8) + (k64 & 7)] = f2bf(p[st][r]);
    }
  f32x4 ctxa[4] = {zf, zf, zf, zf};
#pragma unroll
  for (int ks = 0; ks < 2; ks++) {
    bf16x8 pf = *(const bf16x8*)&Ps[w * 1024 + lr * 64 + (((ks * 4 + lg) ^ (lr & 7)) * 8)];
    int kstart = base + ks * 32 + lg * 8;
#pragma unroll
    for (int c2 = 0; c2 < 4; c2++) {
      const u16* vp = vgt + (size_t)(hh * DHEAD + c2 * 16 + lr) * S_LEN + kstart;
      ctxa[c2] = __builtin_amdgcn_mfma_f32_16x16x32_bf16(pf, *(const bf16x8*)vp, ctxa[c2], 0, 0, 0);
    }
  }
  int pidx = (hh * 16 + c) * 4 + w;
  if (lg < 2) {
#pragma unroll
    for (int r = 0; r < 4; r++) {
      int q = lg * 4 + r;
#pragma unroll
      for (int c2 = 0; c2 < 4; c2++)
        pacc[(size_t)pidx * 512 + q * 64 + c2 * 16 + lr] = ctxa[c2][r];
      if (lr == 0) {
        pm[pidx * 8 + q] = tmax[r];
        pl[pidx * 8 + q] = tsum[r];
      }
    }
  }
}

// ---------------- global-token attention, phase 2: combine 64 partials ----------
__global__ __launch_bounds__(64) void gattn_comb_kernel(
    const float* __restrict__ pm, const float* __restrict__ pl,
    const float* __restrict__ pacc, u16* __restrict__ ctx) {
  int gi = blockIdx.x / NHEAD, hh = blockIdx.x % NHEAD;
  int d = threadIdx.x;
  float M = -1e30f, L = 0.f, A = 0.f;
  for (int i = 0; i < 64; i++) {
    int pidx = hh * 64 + i;
    float m_i = pm[pidx * 8 + gi];
    float l_i = pl[pidx * 8 + gi];
    float a_i = pacc[(size_t)pidx * 512 + gi * 64 + d];
    if (m_i > M) {
      float sc = __expf(M - m_i);
      A = A * sc + a_i;
      L = L * sc + l_i;
      M = m_i;
    } else {
      float sc = __expf(m_i - M);
      A += a_i * sc;
      L += l_i * sc;
    }
  }
  ctx[(size_t)gi * GSTRIDE * DMODEL + hh * DHEAD + d] = f2bf(A / L);
}

// ---------------- CLS pooling + output projection -----------------
__global__ __launch_bounds__(128) void cls_out_kernel(
    const float* __restrict__ h, const float* __restrict__ ow,
    const float* __restrict__ ob, float* __restrict__ y) {
  __shared__ float hs[DMODEL];
  int wi = blockIdx.x;
  int tid = threadIdx.x;
  for (int i = tid; i < DMODEL; i += 128) hs[i] = h[(size_t)wi * GSTRIDE * DMODEL + i];
  __syncthreads();
  float a = ob[tid];
  for (int d = 0; d < DMODEL; d++) a += hs[d] * ow[d * 128 + tid];
  y[wi * 128 + tid] = a;
}

// ---------------- host launch ----------------
extern "C" void kernel_launch(void* const* d_in, const int* in_sizes, int n_in,
                              void* d_out, int out_size, void* d_ws, size_t ws_size,
                              hipStream_t stream) {
  const int*   x      = (const int*)d_in[0];
  const int*   xmask  = (const int*)d_in[1];
  const float* wemb   = (const float*)d_in[2];
  const float* pemb   = (const float*)d_in[3];
  const float* emb_g  = (const float*)d_in[4];
  const float* emb_b  = (const float*)d_in[5];
  const float* Wq     = (const float*)d_in[6];
  const float* bq     = (const float*)d_in[7];
  const float* Wk     = (const float*)d_in[8];
  const float* bk     = (const float*)d_in[9];
  const float* Wv     = (const float*)d_in[10];
  const float* bv     = (const float*)d_in[11];
  const float* Wo     = (const float*)d_in[12];
  const float* bo     = (const float*)d_in[13];
  const float* Wqg    = (const float*)d_in[14];
  const float* bqg    = (const float*)d_in[15];
  const float* Wkg    = (const float*)d_in[16];
  const float* bkg    = (const float*)d_in[17];
  const float* Wvg    = (const float*)d_in[18];
  const float* bvg    = (const float*)d_in[19];
  const float* ln1_g  = (const float*)d_in[20];
  const float* ln1_b  = (const float*)d_in[21];
  const float* W1     = (const float*)d_in[22];
  const float* b1     = (const float*)d_in[23];
  const float* W2     = (const float*)d_in[24];
  const float* b2     = (const float*)d_in[25];
  const float* ln2_g  = (const float*)d_in[26];
  const float* ln2_b  = (const float*)d_in[27];
  const float* out_w  = (const float*)d_in[28];
  const float* out_b  = (const float*)d_in[29];

  char* wsp = (char*)d_ws;
  float* h   = (float*)wsp;  wsp += (size_t)S_LEN * DMODEL * 4;
  float* tmp = (float*)wsp;  wsp += (size_t)S_LEN * DMODEL * 4;
  u16* ctx = (u16*)wsp;      wsp += (size_t)S_LEN * DMODEL * 2;
  u16* qb  = (u16*)wsp;      wsp += (size_t)S_LEN * DMODEL * 2;
  u16* kb  = (u16*)wsp;      wsp += (size_t)S_LEN * DMODEL * 2;
  u16* vt  = (u16*)wsp;      wsp += (size_t)S_LEN * DMODEL * 2;
  u16* kgb = (u16*)wsp;      wsp += (size_t)S_LEN * DMODEL * 2;
  u16* vgt = (u16*)wsp;      wsp += (size_t)S_LEN * DMODEL * 2;
  u16* mid = (u16*)wsp;      wsp += (size_t)S_LEN * FDIM * 2;
  float* qgb = (float*)wsp;  wsp += (size_t)NGLOB * DMODEL * 4;
  u16* vtg = (u16*)wsp;      wsp += (size_t)DMODEL * 32 * 2;
  float* pm = (float*)wsp;   wsp += (size_t)768 * 8 * 4;
  float* pl = (float*)wsp;   wsp += (size_t)768 * 8 * 4;
  float* pacc = (float*)wsp; wsp += (size_t)768 * 512 * 4;

  embed_ln_kernel<<<S_LEN, 256, 0, stream>>>(x, wemb, pemb, emb_g, emb_b, h);

  const size_t DD = (size_t)DMODEL * DMODEL;
  const size_t DF = (size_t)DMODEL * FDIM;

  for (int l = 0; l < NLAYER; l++) {
    const float* wq  = Wq  + (size_t)l * DD;  const float* bql  = bq  + (size_t)l * DMODEL;
    const float* wk  = Wk  + (size_t)l * DD;  const float* bkl  = bk  + (size_t)l * DMODEL;
    const float* wv  = Wv  + (size_t)l * DD;  const float* bvl  = bv  + (size_t)l * DMODEL;
    const float* wo  = Wo  + (size_t)l * DD;  const float* bol  = bo  + (size_t)l * DMODEL;
    const float* wqg = Wqg + (size_t)l * DD;  const float* bqgl = bqg + (size_t)l * DMODEL;
    const float* wkg = Wkg + (size_t)l * DD;  const float* bkgl = bkg + (size_t)l * DMODEL;
    const float* wvg = Wvg + (size_t)l * DD;  const float* bvgl = bvg + (size_t)l * DMODEL;
    const float* w1  = W1  + (size_t)l * DF;  const float* b1l  = b1  + (size_t)l * FDIM;
    const float* w2  = W2  + (size_t)l * DF;  const float* b2l  = b2  + (size_t)l * DMODEL;

    mm5_kernel<<<dim3(30, 32), 256, 0, stream>>>(
        h, wq, wk, wv, wkg, wvg, bql, bkl, bvl, bkgl, bvgl,
        qb, kb, vt, kgb, vgt, S_LEN, DMODEL);
    qg_proj_kernel<<<NGLOB, 256, 0, stream>>>(h, wqg, bqgl, qgb);
    vtg_kernel<<<(DMODEL * 32) / 256, 256, 0, stream>>>(vt, vtg);

    sliding_attn_kernel<<<NHEAD * 64, 256, 0, stream>>>(qb, kb, vt, vtg, xmask, ctx);
    gattn_part_kernel<<<dim3(NHEAD, 16), 256, 0, stream>>>(qgb, kgb, vgt, xmask, pm, pl, pacc);
    gattn_comb_kernel<<<NGLOB * NHEAD, 64, 0, stream>>>(pm, pl, pacc, ctx);

    mm_kernel<0, 0, u16><<<dim3(6, 32), 256, 0, stream>>>(ctx, wo, bol, tmp, S_LEN, DMODEL, DMODEL);
    add_ln_kernel<<<S_LEN, 256, 0, stream>>>(h, tmp, ln1_g + (size_t)l * DMODEL, ln1_b + (size_t)l * DMODEL);

    mm_kernel<1, 1, float><<<dim3(24, 32), 256, 0, stream>>>(h, w1, b1l, mid, S_LEN, FDIM, DMODEL);
    mm_kernel<0, 0, u16><<<dim3(6, 32), 256, 0, stream>>>(mid, w2, b2l, tmp, S_LEN, DMODEL, FDIM);
    add_ln_kernel<<<S_LEN, 256, 0, stream>>>(h, tmp, ln2_g + (size_t)l * DMODEL, ln2_b + (size_t)l * DMODEL);
  }

  cls_out_kernel<<<NGLOB, 128, 0, stream>>>(h, out_w, out_b, (float*)d_out);
}

// Round 4
// 4354.744 us; speedup vs baseline: 9.9587x; 1.2490x over previous
//
#include <hip/hip_runtime.h>
#include <cstddef>

#define S_LEN   4096
#define DMODEL  768
#define NHEAD   12
#define DHEAD   64
#define FDIM    3072
#define NLAYER  12
#define WIN     256
#define NGLOB   8
#define GSTRIDE 512

typedef short bf16x8 __attribute__((ext_vector_type(8)));
typedef float f32x4 __attribute__((ext_vector_type(4)));
typedef unsigned short u16;

__device__ __forceinline__ u16 f2bf(float f) {
  unsigned u = __builtin_bit_cast(unsigned, f);
  return (u16)((u + 0x7FFFu + ((u >> 16) & 1u)) >> 16);
}
__device__ __forceinline__ float bf2f(u16 s) {
  unsigned u = ((unsigned)s) << 16;
  return __builtin_bit_cast(float, u);
}

__device__ __forceinline__ float wave_sum(float v) {
#pragma unroll
  for (int off = 32; off > 0; off >>= 1) v += __shfl_xor(v, off);
  return v;
}

__device__ __forceinline__ float block_sum256(float v, float* sbuf) {
  v = wave_sum(v);
  int w = threadIdx.x >> 6;
  __syncthreads();
  if ((threadIdx.x & 63) == 0) sbuf[w] = v;
  __syncthreads();
  return sbuf[0] + sbuf[1] + sbuf[2] + sbuf[3];
}

// ---------------- embedding + LN (writes f32 h and bf16 hb) ----------------
__global__ __launch_bounds__(256) void embed_ln_kernel(
    const int* __restrict__ x, const float* __restrict__ wemb,
    const float* __restrict__ pemb, const float* __restrict__ gg,
    const float* __restrict__ bb, float* __restrict__ h, u16* __restrict__ hb) {
  __shared__ float sbuf[4];
  int s = blockIdx.x, tid = threadIdx.x;
  int idx = x[s];
  float vals[3];
#pragma unroll
  for (int i = 0; i < 3; i++) {
    int d = tid + i * 256;
    vals[i] = wemb[(size_t)idx * DMODEL + d] + pemb[(size_t)s * DMODEL + d];
  }
  float mean = block_sum256(vals[0] + vals[1] + vals[2], sbuf) * (1.0f / 768.0f);
  float sq = 0.f;
#pragma unroll
  for (int i = 0; i < 3; i++) { float t = vals[i] - mean; sq += t * t; }
  float inv = rsqrtf(block_sum256(sq, sbuf) * (1.0f / 768.0f) + 1e-5f);
#pragma unroll
  for (int i = 0; i < 3; i++) {
    int d = tid + i * 256;
    float r = (vals[i] - mean) * inv * gg[d] + bb[d];
    h[(size_t)s * DMODEL + d] = r;
    hb[(size_t)s * DMODEL + d] = f2bf(r);
  }
}

// ---------------- residual + LN (in place on h; writes hb too) ----------------
__global__ __launch_bounds__(256) void add_ln_kernel(
    float* __restrict__ h, const float* __restrict__ r,
    const float* __restrict__ gg, const float* __restrict__ bb,
    u16* __restrict__ hb) {
  __shared__ float sbuf[4];
  int s = blockIdx.x, tid = threadIdx.x;
  float vals[3];
#pragma unroll
  for (int i = 0; i < 3; i++) {
    int d = tid + i * 256;
    vals[i] = h[(size_t)s * DMODEL + d] + r[(size_t)s * DMODEL + d];
  }
  float mean = block_sum256(vals[0] + vals[1] + vals[2], sbuf) * (1.0f / 768.0f);
  float sq = 0.f;
#pragma unroll
  for (int i = 0; i < 3; i++) { float t = vals[i] - mean; sq += t * t; }
  float inv = rsqrtf(block_sum256(sq, sbuf) * (1.0f / 768.0f) + 1e-5f);
#pragma unroll
  for (int i = 0; i < 3; i++) {
    int d = tid + i * 256;
    float rr = (vals[i] - mean) * inv * gg[d] + bb[d];
    h[(size_t)s * DMODEL + d] = rr;
    hb[(size_t)s * DMODEL + d] = f2bf(rr);
  }
}

// ---------------- per-layer weight convert+transpose: W[K][N] f32 -> Wt[N][K] bf16 ----
// 6x 768x768, then W1 768x3072, then W2 3072x768.  2016 blocks of 64x64 tiles.
__global__ __launch_bounds__(256) void convw_kernel(
    const float* __restrict__ s0, const float* __restrict__ s1,
    const float* __restrict__ s2, const float* __restrict__ s3,
    const float* __restrict__ s4, const float* __restrict__ s5,
    const float* __restrict__ s6, const float* __restrict__ s7,
    u16* __restrict__ d0, u16* __restrict__ d1, u16* __restrict__ d2,
    u16* __restrict__ d3, u16* __restrict__ d4, u16* __restrict__ d5,
    u16* __restrict__ d6, u16* __restrict__ d7) {
  __shared__ float tile[64][65];
  int bid = blockIdx.x;
  const float* src; u16* dst; int K, N, r;
  if (bid < 864) {
    int m = bid / 144; r = bid % 144; K = 768; N = 768;
    switch (m) {
      case 0: src = s0; dst = d0; break;
      case 1: src = s1; dst = d1; break;
      case 2: src = s2; dst = d2; break;
      case 3: src = s3; dst = d3; break;
      case 4: src = s4; dst = d4; break;
      default: src = s5; dst = d5; break;
    }
  } else if (bid < 1440) {
    r = bid - 864; K = 768; N = 3072; src = s6; dst = d6;
  } else {
    r = bid - 1440; K = 3072; N = 768; src = s7; dst = d7;
  }
  int nt = N / 64;
  int tk = (r / nt) * 64, tn = (r % nt) * 64;
  int t = threadIdx.x, tr = t >> 6, tc = t & 63;
#pragma unroll
  for (int i = 0; i < 16; i++)
    tile[i * 4 + tr][tc] = src[(size_t)(tk + i * 4 + tr) * N + tn + tc];
  __syncthreads();
#pragma unroll
  for (int i = 0; i < 16; i++)
    dst[(size_t)(tn + i * 4 + tr) * K + tk + tc] = f2bf(tile[tc][i * 4 + tr]);
}

// ---------------- bf16 MFMA GEMM core (A bf16 [M][K], Wt bf16 [N][K]) ----------------
// 128x128 tile, BK=64, 4 waves (2x2), 16x16x32 MFMA.  XOR-swizzled LDS granules.
template <int ACT, int OUTM>   // OUTM: 0=f32 rm, 1=bf16 rm, 2=bf16 transposed [N][M]
__device__ __forceinline__ void mm_core(const u16* __restrict__ A, const u16* __restrict__ Wt,
                                        const float* __restrict__ bias, void* __restrict__ Cv,
                                        int M, int N, int K, int bm, int bn,
                                        u16* As, u16* Bs) {
  int t = threadIdx.x;
  int wid = t >> 6, lane = t & 63;
  int wr = (wid >> 1) * 64, wc = (wid & 1) * 64;
  int lr = lane & 15, lg = lane >> 4;
  int srow = t >> 1, sg0 = (t & 1) * 4;
  f32x4 acc[4][4];
  f32x4 zf = {0.f, 0.f, 0.f, 0.f};
#pragma unroll
  for (int m = 0; m < 4; m++)
#pragma unroll
    for (int n = 0; n < 4; n++) acc[m][n] = zf;

  const u16* ap0 = A + (size_t)(bm + srow) * K + sg0 * 8;
  const u16* bp0 = Wt + (size_t)(bn + srow) * K + sg0 * 8;
  for (int kt = 0; kt < K; kt += 64) {
    bf16x8 av[4], bv[4];
#pragma unroll
    for (int i = 0; i < 4; i++) av[i] = *(const bf16x8*)(ap0 + kt + i * 8);
#pragma unroll
    for (int i = 0; i < 4; i++) bv[i] = *(const bf16x8*)(bp0 + kt + i * 8);
    __syncthreads();
#pragma unroll
    for (int i = 0; i < 4; i++)
      *(bf16x8*)&As[srow * 64 + (((sg0 + i) ^ (srow & 7)) * 8)] = av[i];
#pragma unroll
    for (int i = 0; i < 4; i++)
      *(bf16x8*)&Bs[srow * 64 + (((sg0 + i) ^ (srow & 7)) * 8)] = bv[i];
    __syncthreads();
#pragma unroll
    for (int ks = 0; ks < 2; ks++) {
      bf16x8 af[4], bfr[4];
#pragma unroll
      for (int m = 0; m < 4; m++)
        af[m] = *(const bf16x8*)&As[(wr + m * 16 + lr) * 64 + (((ks * 4 + lg) ^ (lr & 7)) * 8)];
#pragma unroll
      for (int n = 0; n < 4; n++)
        bfr[n] = *(const bf16x8*)&Bs[(wc + n * 16 + lr) * 64 + (((ks * 4 + lg) ^ (lr & 7)) * 8)];
#pragma unroll
      for (int m = 0; m < 4; m++)
#pragma unroll
        for (int n = 0; n < 4; n++)
          acc[m][n] = __builtin_amdgcn_mfma_f32_16x16x32_bf16(af[m], bfr[n], acc[m][n], 0, 0, 0);
    }
  }
#pragma unroll
  for (int n = 0; n < 4; n++) {
    int col = bn + wc + n * 16 + lr;
    float bb = bias[col];
#pragma unroll
    for (int m = 0; m < 4; m++) {
#pragma unroll
      for (int r = 0; r < 4; r++) {
        int row = bm + wr + m * 16 + lg * 4 + r;
        float xv = acc[m][n][r] + bb;
        if (ACT == 1) xv = 0.5f * xv * (1.0f + erff(xv * 0.70710678118654752f));
        if (OUTM == 0) ((float*)Cv)[(size_t)row * N + col] = xv;
        else if (OUTM == 1) ((u16*)Cv)[(size_t)row * N + col] = f2bf(xv);
        else ((u16*)Cv)[(size_t)col * M + row] = f2bf(xv);
      }
    }
  }
}

template <int ACT, int OUTM>
__global__ __launch_bounds__(256) void mm_kernel(const u16* A, const u16* Wt, const float* bias,
                                                 void* Cv, int M, int N, int K) {
  __shared__ u16 As[128 * 64];
  __shared__ u16 Bs[128 * 64];
  mm_core<ACT, OUTM>(A, Wt, bias, Cv, M, N, K, blockIdx.y * 128, blockIdx.x * 128, As, Bs);
}

// fused q/k/v/kg/vg projections. slots 2 (v) and 4 (vg) store transposed.
__global__ __launch_bounds__(256) void mm5_kernel(
    const u16* A,
    const u16* W0, const u16* W1_, const u16* W2_, const u16* W3, const u16* W4,
    const float* b0, const float* b1, const float* b2, const float* b3, const float* b4,
    u16* C0, u16* C1, u16* C2, u16* C3, u16* C4, int M, int K) {
  __shared__ u16 As[128 * 64];
  __shared__ u16 Bs[128 * 64];
  int which = blockIdx.x / 6;
  int bn = (blockIdx.x % 6) * 128;
  const u16* Ws[5] = {W0, W1_, W2_, W3, W4};
  const float* bs[5] = {b0, b1, b2, b3, b4};
  u16* Cs[5] = {C0, C1, C2, C3, C4};
  if (which == 2 || which == 4)
    mm_core<0, 2>(A, Ws[which], bs[which], Cs[which], M, DMODEL, K, blockIdx.y * 128, bn, As, Bs);
  else
    mm_core<0, 1>(A, Ws[which], bs[which], Cs[which], M, DMODEL, K, blockIdx.y * 128, bn, As, Bs);
}

// ---------------- qg projection (fp32, tiny) ----------------
__global__ __launch_bounds__(256) void qg_proj_kernel(
    const float* __restrict__ h, const float* __restrict__ Wqg,
    const float* __restrict__ bqg, float* __restrict__ qg) {
  __shared__ float hs[DMODEL];
  int gi = blockIdx.x;
  const float* hrow = h + (size_t)gi * GSTRIDE * DMODEL;
  int tid = threadIdx.x;
  for (int i = tid; i < DMODEL; i += 256) hs[i] = hrow[i];
  __syncthreads();
  float a0 = bqg[tid], a1 = bqg[tid + 256], a2 = bqg[tid + 512];
  for (int kk = 0; kk < DMODEL; kk++) {
    float hv = hs[kk];
    a0 += hv * Wqg[(size_t)kk * DMODEL + tid];
    a1 += hv * Wqg[(size_t)kk * DMODEL + tid + 256];
    a2 += hv * Wqg[(size_t)kk * DMODEL + tid + 512];
  }
  qg[gi * DMODEL + tid] = a0;
  qg[gi * DMODEL + tid + 256] = a1;
  qg[gi * DMODEL + tid + 512] = a2;
}

// ---------------- gather global-key columns of Vt, zero-padded to 32 ----------------
__global__ __launch_bounds__(256) void vtg_kernel(const u16* __restrict__ vt, u16* __restrict__ vtg) {
  int tid = blockIdx.x * 256 + threadIdx.x;   // 768*32
  int d = tid >> 5, j = tid & 31;
  vtg[tid] = (j < NGLOB) ? vt[(size_t)d * S_LEN + j * GSTRIDE] : (u16)0;
}

// ---------------- sliding-window flash attention (MFMA) ----------------
__global__ __launch_bounds__(256) void sliding_attn_kernel(
    const u16* __restrict__ qb, const u16* __restrict__ kb,
    const u16* __restrict__ vt, const u16* __restrict__ vtg,
    const int* __restrict__ xmask, u16* __restrict__ ctx) {
  __shared__ u16 Ps[4 * 16 * 64];
  int hh = blockIdx.x >> 6;
  int q0 = (blockIdx.x & 63) * 64;
  int w = threadIdx.x >> 6, lane = threadIdx.x & 63;
  int lr = lane & 15, lg = lane >> 4;
  f32x4 zf = {0.f, 0.f, 0.f, 0.f};

  const u16* qptr = qb + (size_t)(q0 + w * 16 + lr) * DMODEL + hh * DHEAD;
  bf16x8 qf0 = *(const bf16x8*)(qptr + lg * 8);
  bf16x8 qf1 = *(const bf16x8*)(qptr + 32 + lg * 8);

  float m_run[4] = {-1e30f, -1e30f, -1e30f, -1e30f};
  float l_run[4] = {0.f, 0.f, 0.f, 0.f};
  f32x4 ctxa[4] = {zf, zf, zf, zf};

  // ---- global-key tile ----
  {
    int krow = (lr < NGLOB) ? lr * GSTRIDE : 0;
    const u16* kp = kb + (size_t)krow * DMODEL + hh * DHEAD + lg * 8;
    f32x4 sa = __builtin_amdgcn_mfma_f32_16x16x32_bf16(qf0, *(const bf16x8*)kp, zf, 0, 0, 0);
    sa = __builtin_amdgcn_mfma_f32_16x16x32_bf16(qf1, *(const bf16x8*)(kp + 32), sa, 0, 0, 0);
    float p0[4], tmax[4];
#pragma unroll
    for (int r = 0; r < 4; r++) {
      float s = (lr < NGLOB) ? sa[r] * 0.125f : -1e30f;
      p0[r] = s; tmax[r] = s;
    }
#pragma unroll
    for (int o = 8; o; o >>= 1)
#pragma unroll
      for (int r = 0; r < 4; r++) tmax[r] = fmaxf(tmax[r], __shfl_xor(tmax[r], o));
    float tsum[4];
#pragma unroll
    for (int r = 0; r < 4; r++) {
      float mn = fmaxf(m_run[r], tmax[r]);
      m_run[r] = mn;
      p0[r] = __expf(p0[r] - mn);
      tsum[r] = p0[r];
    }
#pragma unroll
    for (int o = 8; o; o >>= 1)
#pragma unroll
      for (int r = 0; r < 4; r++) tsum[r] += __shfl_xor(tsum[r], o);
#pragma unroll
    for (int r = 0; r < 4; r++) l_run[r] = tsum[r];
#pragma unroll
    for (int r = 0; r < 4; r++) {
      int qi = lg * 4 + r;
      Ps[w * 1024 + qi * 64 + (((lr >> 3) ^ (qi & 7)) * 8) + (lr & 7)] = f2bf(p0[r]);
      int k2 = 16 + lr;
      Ps[w * 1024 + qi * 64 + (((k2 >> 3) ^ (qi & 7)) * 8) + (k2 & 7)] = 0;
    }
    bf16x8 pf = *(const bf16x8*)&Ps[w * 1024 + lr * 64 + ((lg ^ (lr & 7)) * 8)];
#pragma unroll
    for (int c2 = 0; c2 < 4; c2++) {
      const u16* vp = vtg + (size_t)(hh * DHEAD + c2 * 16 + lr) * 32 + lg * 8;
      ctxa[c2] = __builtin_amdgcn_mfma_f32_16x16x32_bf16(pf, *(const bf16x8*)vp, ctxa[c2], 0, 0, 0);
    }
  }

  // ---- 9 band tiles of 64 keys ----
  for (int tt = 0; tt < 9; tt++) {
    int base = q0 - WIN + tt * 64;
    if (base + 63 < 0 || base >= S_LEN) continue;
    f32x4 sa[4];
    int keyc[4]; bool vc[4];
#pragma unroll
    for (int c = 0; c < 4; c++) {
      int key = base + c * 16 + lr;
      int krow = key < 0 ? 0 : (key > S_LEN - 1 ? S_LEN - 1 : key);
      vc[c] = (key >= 0) && (key < S_LEN) && ((key & (GSTRIDE - 1)) != 0) && (xmask[krow] != 0);
      keyc[c] = key;
      const u16* kp = kb + (size_t)krow * DMODEL + hh * DHEAD + lg * 8;
      sa[c] = __builtin_amdgcn_mfma_f32_16x16x32_bf16(qf0, *(const bf16x8*)kp, zf, 0, 0, 0);
      sa[c] = __builtin_amdgcn_mfma_f32_16x16x32_bf16(qf1, *(const bf16x8*)(kp + 32), sa[c], 0, 0, 0);
    }
    float p[4][4], tmax[4] = {-1e30f, -1e30f, -1e30f, -1e30f};
#pragma unroll
    for (int c = 0; c < 4; c++)
#pragma unroll
      for (int r = 0; r < 4; r++) {
        int qrow = q0 + w * 16 + lg * 4 + r;
        int dd = keyc[c] - qrow;
        float s = (vc[c] && dd >= -WIN && dd <= WIN) ? sa[c][r] * 0.125f : -1e30f;
        p[c][r] = s;
        tmax[r] = fmaxf(tmax[r], s);
      }
#pragma unroll
    for (int o = 8; o; o >>= 1)
#pragma unroll
      for (int r = 0; r < 4; r++) tmax[r] = fmaxf(tmax[r], __shfl_xor(tmax[r], o));
    float sc[4], tsum[4] = {0.f, 0.f, 0.f, 0.f};
#pragma unroll
    for (int r = 0; r < 4; r++) {
      float mn = fmaxf(m_run[r], tmax[r]);
      sc[r] = __expf(m_run[r] - mn);
      m_run[r] = mn;
    }
#pragma unroll
    for (int c = 0; c < 4; c++)
#pragma unroll
      for (int r = 0; r < 4; r++) {
        p[c][r] = __expf(p[c][r] - m_run[r]);
        tsum[r] += p[c][r];
      }
#pragma unroll
    for (int o = 8; o; o >>= 1)
#pragma unroll
      for (int r = 0; r < 4; r++) tsum[r] += __shfl_xor(tsum[r], o);
#pragma unroll
    for (int r = 0; r < 4; r++) l_run[r] = l_run[r] * sc[r] + tsum[r];
#pragma unroll
    for (int c2 = 0; c2 < 4; c2++)
#pragma unroll
      for (int r = 0; r < 4; r++) ctxa[c2][r] *= sc[r];
#pragma unroll
    for (int c = 0; c < 4; c++)
#pragma unroll
      for (int r = 0; r < 4; r++) {
        int qi = lg * 4 + r, k64 = c * 16 + lr;
        Ps[w * 1024 + qi * 64 + (((k64 >> 3) ^ (qi & 7)) * 8) + (k64 & 7)] = f2bf(p[c][r]);
      }
#pragma unroll
    for (int ks = 0; ks < 2; ks++) {
      bf16x8 pf = *(const bf16x8*)&Ps[w * 1024 + lr * 64 + (((ks * 4 + lg) ^ (lr & 7)) * 8)];
      int kstart = base + ks * 32 + lg * 8;
      int kc = kstart < 0 ? 0 : (kstart > S_LEN - 8 ? S_LEN - 8 : kstart);
#pragma unroll
      for (int c2 = 0; c2 < 4; c2++) {
        const u16* vp = vt + (size_t)(hh * DHEAD + c2 * 16 + lr) * S_LEN + kc;
        ctxa[c2] = __builtin_amdgcn_mfma_f32_16x16x32_bf16(pf, *(const bf16x8*)vp, ctxa[c2], 0, 0, 0);
      }
    }
  }

#pragma unroll
  for (int c2 = 0; c2 < 4; c2++)
#pragma unroll
    for (int r = 0; r < 4; r++) {
      int qrow = q0 + w * 16 + lg * 4 + r;
      ctx[(size_t)qrow * DMODEL + hh * DHEAD + c2 * 16 + lr] = f2bf(ctxa[c2][r] / l_run[r]);
    }
}

// ---------------- global-token attention, phase 1 ----------------
__global__ __launch_bounds__(256) void gattn_part_kernel(
    const float* __restrict__ qg, const u16* __restrict__ kg,
    const u16* __restrict__ vgt, const int* __restrict__ xmask,
    float* __restrict__ pm, float* __restrict__ pl, float* __restrict__ pacc) {
  __shared__ u16 Ps[4 * 16 * 64];
  int hh = blockIdx.x;
  int c  = blockIdx.y;
  int w = threadIdx.x >> 6, lane = threadIdx.x & 63;
  int lr = lane & 15, lg = lane >> 4;
  int base = c * 256 + w * 64;
  f32x4 zf = {0.f, 0.f, 0.f, 0.f};

  bf16x8 qf0, qf1;
  {
    const float* qp = qg + (size_t)(lr & 7) * DMODEL + hh * DHEAD;
    bool real = lr < 8;
#pragma unroll
    for (int j = 0; j < 8; j++) {
      qf0[j] = real ? (short)f2bf(0.125f * qp[lg * 8 + j]) : (short)0;
      qf1[j] = real ? (short)f2bf(0.125f * qp[32 + lg * 8 + j]) : (short)0;
    }
  }

  f32x4 sa[4];
  bool vc[4];
#pragma unroll
  for (int st = 0; st < 4; st++) {
    int key = base + st * 16 + lr;
    vc[st] = (xmask[key] != 0) || ((key & (GSTRIDE - 1)) == 0);
    const u16* kp = kg + (size_t)key * DMODEL + hh * DHEAD + lg * 8;
    sa[st] = __builtin_amdgcn_mfma_f32_16x16x32_bf16(qf0, *(const bf16x8*)kp, zf, 0, 0, 0);
    sa[st] = __builtin_amdgcn_mfma_f32_16x16x32_bf16(qf1, *(const bf16x8*)(kp + 32), sa[st], 0, 0, 0);
  }
  float p[4][4], tmax[4] = {-1e30f, -1e30f, -1e30f, -1e30f};
#pragma unroll
  for (int st = 0; st < 4; st++)
#pragma unroll
    for (int r = 0; r < 4; r++) {
      float s = vc[st] ? sa[st][r] : -1e30f;
      p[st][r] = s;
      tmax[r] = fmaxf(tmax[r], s);
    }
#pragma unroll
  for (int o = 8; o; o >>= 1)
#pragma unroll
    for (int r = 0; r < 4; r++) tmax[r] = fmaxf(tmax[r], __shfl_xor(tmax[r], o));
  float tsum[4] = {0.f, 0.f, 0.f, 0.f};
#pragma unroll
  for (int st = 0; st < 4; st++)
#pragma unroll
    for (int r = 0; r < 4; r++) {
      float pv = vc[st] ? __expf(p[st][r] - tmax[r]) : 0.f;
      p[st][r] = pv;
      tsum[r] += pv;
    }
#pragma unroll
  for (int o = 8; o; o >>= 1)
#pragma unroll
    for (int r = 0; r < 4; r++) tsum[r] += __shfl_xor(tsum[r], o);
#pragma unroll
  for (int st = 0; st < 4; st++)
#pragma unroll
    for (int r = 0; r < 4; r++) {
      int qi = lg * 4 + r, k64 = st * 16 + lr;
      Ps[w * 1024 + qi * 64 + (((k64 >> 3) ^ (qi & 7)) * 8) + (k64 & 7)] = f2bf(p[st][r]);
    }
  f32x4 ctxa[4] = {zf, zf, zf, zf};
#pragma unroll
  for (int ks = 0; ks < 2; ks++) {
    bf16x8 pf = *(const bf16x8*)&Ps[w * 1024 + lr * 64 + (((ks * 4 + lg) ^ (lr & 7)) * 8)];
    int kstart = base + ks * 32 + lg * 8;
#pragma unroll
    for (int c2 = 0; c2 < 4; c2++) {
      const u16* vp = vgt + (size_t)(hh * DHEAD + c2 * 16 + lr) * S_LEN + kstart;
      ctxa[c2] = __builtin_amdgcn_mfma_f32_16x16x32_bf16(pf, *(const bf16x8*)vp, ctxa[c2], 0, 0, 0);
    }
  }
  int pidx = (hh * 16 + c) * 4 + w;
  if (lg < 2) {
#pragma unroll
    for (int r = 0; r < 4; r++) {
      int q = lg * 4 + r;
#pragma unroll
      for (int c2 = 0; c2 < 4; c2++)
        pacc[(size_t)pidx * 512 + q * 64 + c2 * 16 + lr] = ctxa[c2][r];
      if (lr == 0) {
        pm[pidx * 8 + q] = tmax[r];
        pl[pidx * 8 + q] = tsum[r];
      }
    }
  }
}

// ---------------- global-token attention, phase 2 ----------------
__global__ __launch_bounds__(64) void gattn_comb_kernel(
    const float* __restrict__ pm, const float* __restrict__ pl,
    const float* __restrict__ pacc, u16* __restrict__ ctx) {
  int gi = blockIdx.x / NHEAD, hh = blockIdx.x % NHEAD;
  int d = threadIdx.x;
  float M = -1e30f, L = 0.f, A = 0.f;
  for (int i = 0; i < 64; i++) {
    int pidx = hh * 64 + i;
    float m_i = pm[pidx * 8 + gi];
    float l_i = pl[pidx * 8 + gi];
    float a_i = pacc[(size_t)pidx * 512 + gi * 64 + d];
    if (m_i > M) {
      float sc = __expf(M - m_i);
      A = A * sc + a_i;
      L = L * sc + l_i;
      M = m_i;
    } else {
      float sc = __expf(m_i - M);
      A += a_i * sc;
      L += l_i * sc;
    }
  }
  ctx[(size_t)gi * GSTRIDE * DMODEL + hh * DHEAD + d] = f2bf(A / L);
}

// ---------------- CLS pooling + output projection -----------------
__global__ __launch_bounds__(128) void cls_out_kernel(
    const float* __restrict__ h, const float* __restrict__ ow,
    const float* __restrict__ ob, float* __restrict__ y) {
  __shared__ float hs[DMODEL];
  int wi = blockIdx.x;
  int tid = threadIdx.x;
  for (int i = tid; i < DMODEL; i += 128) hs[i] = h[(size_t)wi * GSTRIDE * DMODEL + i];
  __syncthreads();
  float a = ob[tid];
  for (int d = 0; d < DMODEL; d++) a += hs[d] * ow[d * 128 + tid];
  y[wi * 128 + tid] = a;
}

// ---------------- host launch ----------------
extern "C" void kernel_launch(void* const* d_in, const int* in_sizes, int n_in,
                              void* d_out, int out_size, void* d_ws, size_t ws_size,
                              hipStream_t stream) {
  const int*   x      = (const int*)d_in[0];
  const int*   xmask  = (const int*)d_in[1];
  const float* wemb   = (const float*)d_in[2];
  const float* pemb   = (const float*)d_in[3];
  const float* emb_g  = (const float*)d_in[4];
  const float* emb_b  = (const float*)d_in[5];
  const float* Wq     = (const float*)d_in[6];
  const float* bq     = (const float*)d_in[7];
  const float* Wk     = (const float*)d_in[8];
  const float* bk     = (const float*)d_in[9];
  const float* Wv     = (const float*)d_in[10];
  const float* bv     = (const float*)d_in[11];
  const float* Wo     = (const float*)d_in[12];
  const float* bo     = (const float*)d_in[13];
  const float* Wqg    = (const float*)d_in[14];
  const float* bqg    = (const float*)d_in[15];
  const float* Wkg    = (const float*)d_in[16];
  const float* bkg    = (const float*)d_in[17];
  const float* Wvg    = (const float*)d_in[18];
  const float* bvg    = (const float*)d_in[19];
  const float* ln1_g  = (const float*)d_in[20];
  const float* ln1_b  = (const float*)d_in[21];
  const float* W1     = (const float*)d_in[22];
  const float* b1     = (const float*)d_in[23];
  const float* W2     = (const float*)d_in[24];
  const float* b2     = (const float*)d_in[25];
  const float* ln2_g  = (const float*)d_in[26];
  const float* ln2_b  = (const float*)d_in[27];
  const float* out_w  = (const float*)d_in[28];
  const float* out_b  = (const float*)d_in[29];

  const size_t DD = (size_t)DMODEL * DMODEL;
  const size_t DF = (size_t)DMODEL * FDIM;

  char* wsp = (char*)d_ws;
  float* h   = (float*)wsp;  wsp += (size_t)S_LEN * DMODEL * 4;
  float* tmp = (float*)wsp;  wsp += (size_t)S_LEN * DMODEL * 4;
  u16* hb  = (u16*)wsp;      wsp += (size_t)S_LEN * DMODEL * 2;
  u16* ctx = (u16*)wsp;      wsp += (size_t)S_LEN * DMODEL * 2;
  u16* qb  = (u16*)wsp;      wsp += (size_t)S_LEN * DMODEL * 2;
  u16* kb  = (u16*)wsp;      wsp += (size_t)S_LEN * DMODEL * 2;
  u16* vt  = (u16*)wsp;      wsp += (size_t)S_LEN * DMODEL * 2;
  u16* kgb = (u16*)wsp;      wsp += (size_t)S_LEN * DMODEL * 2;
  u16* vgt = (u16*)wsp;      wsp += (size_t)S_LEN * DMODEL * 2;
  u16* mid = (u16*)wsp;      wsp += (size_t)S_LEN * FDIM * 2;
  float* qgb = (float*)wsp;  wsp += (size_t)NGLOB * DMODEL * 4;
  u16* vtg = (u16*)wsp;      wsp += (size_t)DMODEL * 32 * 2;
  float* pm = (float*)wsp;   wsp += (size_t)768 * 8 * 4;
  float* pl = (float*)wsp;   wsp += (size_t)768 * 8 * 4;
  float* pacc = (float*)wsp; wsp += (size_t)768 * 512 * 4;
  u16* wtb = (u16*)wsp;      wsp += (6 * DD + 2 * DF) * 2;
  u16* wqT  = wtb;
  u16* wkT  = wtb + 1 * DD;
  u16* wvT  = wtb + 2 * DD;
  u16* wkgT = wtb + 3 * DD;
  u16* wvgT = wtb + 4 * DD;
  u16* woT  = wtb + 5 * DD;
  u16* w1T  = wtb + 6 * DD;
  u16* w2T  = wtb + 6 * DD + DF;

  embed_ln_kernel<<<S_LEN, 256, 0, stream>>>(x, wemb, pemb, emb_g, emb_b, h, hb);

  for (int l = 0; l < NLAYER; l++) {
    const float* wq  = Wq  + (size_t)l * DD;  const float* bql  = bq  + (size_t)l * DMODEL;
    const float* wk  = Wk  + (size_t)l * DD;  const float* bkl  = bk  + (size_t)l * DMODEL;
    const float* wv  = Wv  + (size_t)l * DD;  const float* bvl  = bv  + (size_t)l * DMODEL;
    const float* wo  = Wo  + (size_t)l * DD;  const float* bol  = bo  + (size_t)l * DMODEL;
    const float* wqg = Wqg + (size_t)l * DD;  const float* bqgl = bqg + (size_t)l * DMODEL;
    const float* wkg = Wkg + (size_t)l * DD;  const float* bkgl = bkg + (size_t)l * DMODEL;
    const float* wvg = Wvg + (size_t)l * DD;  const float* bvgl = bvg + (size_t)l * DMODEL;
    const float* w1  = W1  + (size_t)l * DF;  const float* b1l  = b1  + (size_t)l * FDIM;
    const float* w2  = W2  + (size_t)l * DF;  const float* b2l  = b2  + (size_t)l * DMODEL;

    convw_kernel<<<2016, 256, 0, stream>>>(wq, wk, wv, wkg, wvg, wo, w1, w2,
                                           wqT, wkT, wvT, wkgT, wvgT, woT, w1T, w2T);

    mm5_kernel<<<dim3(30, 32), 256, 0, stream>>>(
        hb, wqT, wkT, wvT, wkgT, wvgT, bql, bkl, bvl, bkgl, bvgl,
        qb, kb, vt, kgb, vgt, S_LEN, DMODEL);
    qg_proj_kernel<<<NGLOB, 256, 0, stream>>>(h, wqg, bqgl, qgb);
    vtg_kernel<<<(DMODEL * 32) / 256, 256, 0, stream>>>(vt, vtg);

    sliding_attn_kernel<<<NHEAD * 64, 256, 0, stream>>>(qb, kb, vt, vtg, xmask, ctx);
    gattn_part_kernel<<<dim3(NHEAD, 16), 256, 0, stream>>>(qgb, kgb, vgt, xmask, pm, pl, pacc);
    gattn_comb_kernel<<<NGLOB * NHEAD, 64, 0, stream>>>(pm, pl, pacc, ctx);

    mm_kernel<0, 0><<<dim3(6, 32), 256, 0, stream>>>(ctx, woT, bol, tmp, S_LEN, DMODEL, DMODEL);
    add_ln_kernel<<<S_LEN, 256, 0, stream>>>(h, tmp, ln1_g + (size_t)l * DMODEL,
                                             ln1_b + (size_t)l * DMODEL, hb);

    mm_kernel<1, 1><<<dim3(24, 32), 256, 0, stream>>>(hb, w1T, b1l, mid, S_LEN, FDIM, DMODEL);
    mm_kernel<0, 0><<<dim3(6, 32), 256, 0, stream>>>(mid, w2T, b2l, tmp, S_LEN, DMODEL, FDIM);
    add_ln_kernel<<<S_LEN, 256, 0, stream>>>(h, tmp, ln2_g + (size_t)l * DMODEL,
                                             ln2_b + (size_t)l * DMODEL, hb);
  }

  cls_out_kernel<<<NGLOB, 128, 0, stream>>>(h, out_w, out_b, (float*)d_out);
}

// Round 5
// 3946.695 us; speedup vs baseline: 10.9884x; 1.1034x over previous
//
#include <hip/hip_runtime.h>
#include <cstddef>

#define S_LEN   4096
#define DMODEL  768
#define NHEAD   12
#define DHEAD   64
#define FDIM    3072
#define NLAYER  12
#define WIN     256
#define NGLOB   8
#define GSTRIDE 512

typedef short bf16x8 __attribute__((ext_vector_type(8)));
typedef float f32x4 __attribute__((ext_vector_type(4)));
typedef unsigned short u16;

__device__ __forceinline__ u16 f2bf(float f) {
  unsigned u = __builtin_bit_cast(unsigned, f);
  return (u16)((u + 0x7FFFu + ((u >> 16) & 1u)) >> 16);
}
__device__ __forceinline__ float bf2f(u16 s) {
  unsigned u = ((unsigned)s) << 16;
  return __builtin_bit_cast(float, u);
}

// async global->LDS, 16B per lane; lds base must be wave-uniform (HW adds lane*16)
__device__ __forceinline__ void gload16(const void* g, void* l) {
  __builtin_amdgcn_global_load_lds(
      (const __attribute__((address_space(1))) void*)g,
      (__attribute__((address_space(3))) void*)l, 16, 0, 0);
}

__device__ __forceinline__ float wave_sum(float v) {
#pragma unroll
  for (int off = 32; off > 0; off >>= 1) v += __shfl_xor(v, off);
  return v;
}

__device__ __forceinline__ float block_sum256(float v, float* sbuf) {
  v = wave_sum(v);
  int w = threadIdx.x >> 6;
  __syncthreads();
  if ((threadIdx.x & 63) == 0) sbuf[w] = v;
  __syncthreads();
  return sbuf[0] + sbuf[1] + sbuf[2] + sbuf[3];
}

// ---------------- embedding + LN (writes f32 h and bf16 hb) ----------------
__global__ __launch_bounds__(256) void embed_ln_kernel(
    const int* __restrict__ x, const float* __restrict__ wemb,
    const float* __restrict__ pemb, const float* __restrict__ gg,
    const float* __restrict__ bb, float* __restrict__ h, u16* __restrict__ hb) {
  __shared__ float sbuf[4];
  int s = blockIdx.x, tid = threadIdx.x;
  int idx = x[s];
  float vals[3];
#pragma unroll
  for (int i = 0; i < 3; i++) {
    int d = tid + i * 256;
    vals[i] = wemb[(size_t)idx * DMODEL + d] + pemb[(size_t)s * DMODEL + d];
  }
  float mean = block_sum256(vals[0] + vals[1] + vals[2], sbuf) * (1.0f / 768.0f);
  float sq = 0.f;
#pragma unroll
  for (int i = 0; i < 3; i++) { float t = vals[i] - mean; sq += t * t; }
  float inv = rsqrtf(block_sum256(sq, sbuf) * (1.0f / 768.0f) + 1e-5f);
#pragma unroll
  for (int i = 0; i < 3; i++) {
    int d = tid + i * 256;
    float r = (vals[i] - mean) * inv * gg[d] + bb[d];
    h[(size_t)s * DMODEL + d] = r;
    hb[(size_t)s * DMODEL + d] = f2bf(r);
  }
}

// ---------------- residual + LN (in place on h; writes hb too) ----------------
__global__ __launch_bounds__(256) void add_ln_kernel(
    float* __restrict__ h, const float* __restrict__ r,
    const float* __restrict__ gg, const float* __restrict__ bb,
    u16* __restrict__ hb) {
  __shared__ float sbuf[4];
  int s = blockIdx.x, tid = threadIdx.x;
  float vals[3];
#pragma unroll
  for (int i = 0; i < 3; i++) {
    int d = tid + i * 256;
    vals[i] = h[(size_t)s * DMODEL + d] + r[(size_t)s * DMODEL + d];
  }
  float mean = block_sum256(vals[0] + vals[1] + vals[2], sbuf) * (1.0f / 768.0f);
  float sq = 0.f;
#pragma unroll
  for (int i = 0; i < 3; i++) { float t = vals[i] - mean; sq += t * t; }
  float inv = rsqrtf(block_sum256(sq, sbuf) * (1.0f / 768.0f) + 1e-5f);
#pragma unroll
  for (int i = 0; i < 3; i++) {
    int d = tid + i * 256;
    float rr = (vals[i] - mean) * inv * gg[d] + bb[d];
    h[(size_t)s * DMODEL + d] = rr;
    hb[(size_t)s * DMODEL + d] = f2bf(rr);
  }
}

// ---------------- ALL-layer weight convert+transpose: W[K][N] f32 -> Wt[N][K] bf16 ----
// grid (2016, NLAYER): per layer 6x 768x768 (864 blk), W1 768x3072 (576), W2 3072x768 (576).
#define DD_ ((size_t)DMODEL * DMODEL)
#define DF_ ((size_t)DMODEL * FDIM)
#define WSTRIDE (6 * DD_ + 2 * DF_)
__global__ __launch_bounds__(256) void convw_kernel(
    const float* __restrict__ Wq, const float* __restrict__ Wk,
    const float* __restrict__ Wv, const float* __restrict__ Wkg,
    const float* __restrict__ Wvg, const float* __restrict__ Wo,
    const float* __restrict__ W1, const float* __restrict__ W2,
    u16* __restrict__ wt) {
  __shared__ float tile[64][65];
  int l = blockIdx.y;
  int bid = blockIdx.x;
  const float* src; u16* dst; int K, N, r;
  u16* base = wt + (size_t)l * WSTRIDE;
  if (bid < 864) {
    int m = bid / 144; r = bid % 144; K = 768; N = 768;
    switch (m) {
      case 0: src = Wq  + l * DD_; dst = base;          break;
      case 1: src = Wk  + l * DD_; dst = base + 1 * DD_; break;
      case 2: src = Wv  + l * DD_; dst = base + 2 * DD_; break;
      case 3: src = Wkg + l * DD_; dst = base + 3 * DD_; break;
      case 4: src = Wvg + l * DD_; dst = base + 4 * DD_; break;
      default: src = Wo + l * DD_; dst = base + 5 * DD_; break;
    }
  } else if (bid < 1440) {
    r = bid - 864; K = 768; N = 3072; src = W1 + l * DF_; dst = base + 6 * DD_;
  } else {
    r = bid - 1440; K = 3072; N = 768; src = W2 + l * DF_; dst = base + 6 * DD_ + DF_;
  }
  int nt = N / 64;
  int tk = (r / nt) * 64, tn = (r % nt) * 64;
  int t = threadIdx.x, tr = t >> 6, tc = t & 63;
#pragma unroll
  for (int i = 0; i < 16; i++)
    tile[i * 4 + tr][tc] = src[(size_t)(tk + i * 4 + tr) * N + tn + tc];
  __syncthreads();
#pragma unroll
  for (int i = 0; i < 16; i++)
    dst[(size_t)(tn + i * 4 + tr) * K + tk + tc] = f2bf(tile[tc][i * 4 + tr]);
}

// ---------------- bf16 MFMA GEMM core (A bf16 [M][K], Wt bf16 [N][K]) ----------------
// 128x128 tile, BK=64, 4 waves (2x2), 16x16x32 MFMA.
// Staging: global_load_lds w=16, linear LDS dest, inverse-swizzled global source.
// LDS[row][g] holds global granule g ^ (row&7); ds_read applies the same XOR.
template <int ACT, int OUTM>   // OUTM: 0=f32 rm, 1=bf16 rm, 2=bf16 transposed [N][M]
__device__ __forceinline__ void mm_core(const u16* __restrict__ A, const u16* __restrict__ Wt,
                                        const float* __restrict__ bias, void* __restrict__ Cv,
                                        int M, int N, int K, int bm, int bn,
                                        u16* As, u16* Bs) {
  int t = threadIdx.x;
  int wid = t >> 6, lane = t & 63;
  int wr = (wid >> 1) * 64, wc = (wid & 1) * 64;
  int lr = lane & 15, lg = lane >> 4;
  f32x4 acc[4][4];
  f32x4 zf = {0.f, 0.f, 0.f, 0.f};
#pragma unroll
  for (int m = 0; m < 4; m++)
#pragma unroll
    for (int n = 0; n < 4; n++) acc[m][n] = zf;

  // staging: instr j covers rows j*32..j*32+31; wave covers 8 rows; lane -> row +(lane>>3),
  // source k-granule = (lane&7) ^ (row&7) = (lane&7) ^ (lane>>3)  (j*32, wid*8 are mult of 8)
  int srow = wid * 8 + (lane >> 3);
  int sgr = (lane & 7) ^ (lane >> 3);
  const u16* aSrc = A + (size_t)(bm + srow) * K + sgr * 8;
  const u16* bSrc = Wt + (size_t)(bn + srow) * K + sgr * 8;
  u16* aDst = As + (size_t)(wid * 8) * 64;
  u16* bDst = Bs + (size_t)(wid * 8) * 64;

  for (int kt = 0; kt < K; kt += 64) {
    __syncthreads();
#pragma unroll
    for (int j = 0; j < 4; j++)
      gload16(aSrc + kt + (size_t)j * 32 * K, aDst + (size_t)j * 32 * 64);
#pragma unroll
    for (int j = 0; j < 4; j++)
      gload16(bSrc + kt + (size_t)j * 32 * K, bDst + (size_t)j * 32 * 64);
    __syncthreads();
#pragma unroll
    for (int ks = 0; ks < 2; ks++) {
      bf16x8 af[4], bfr[4];
#pragma unroll
      for (int m = 0; m < 4; m++)
        af[m] = *(const bf16x8*)&As[(wr + m * 16 + lr) * 64 + (((ks * 4 + lg) ^ (lr & 7)) * 8)];
#pragma unroll
      for (int n = 0; n < 4; n++)
        bfr[n] = *(const bf16x8*)&Bs[(wc + n * 16 + lr) * 64 + (((ks * 4 + lg) ^ (lr & 7)) * 8)];
#pragma unroll
      for (int m = 0; m < 4; m++)
#pragma unroll
        for (int n = 0; n < 4; n++)
          acc[m][n] = __builtin_amdgcn_mfma_f32_16x16x32_bf16(af[m], bfr[n], acc[m][n], 0, 0, 0);
    }
  }
#pragma unroll
  for (int n = 0; n < 4; n++) {
    int col = bn + wc + n * 16 + lr;
    float bb = bias[col];
#pragma unroll
    for (int m = 0; m < 4; m++) {
#pragma unroll
      for (int r = 0; r < 4; r++) {
        int row = bm + wr + m * 16 + lg * 4 + r;
        float xv = acc[m][n][r] + bb;
        if (ACT == 1) xv = 0.5f * xv * (1.0f + erff(xv * 0.70710678118654752f));
        if (OUTM == 0) ((float*)Cv)[(size_t)row * N + col] = xv;
        else if (OUTM == 1) ((u16*)Cv)[(size_t)row * N + col] = f2bf(xv);
        else ((u16*)Cv)[(size_t)col * M + row] = f2bf(xv);
      }
    }
  }
}

template <int ACT, int OUTM>
__global__ __launch_bounds__(256) void mm_kernel(const u16* A, const u16* Wt, const float* bias,
                                                 void* Cv, int M, int N, int K) {
  __shared__ u16 As[128 * 64];
  __shared__ u16 Bs[128 * 64];
  mm_core<ACT, OUTM>(A, Wt, bias, Cv, M, N, K, blockIdx.y * 128, blockIdx.x * 128, As, Bs);
}

// fused q/k/v/kg/vg projections. slots 2 (v) and 4 (vg) store transposed.
__global__ __launch_bounds__(256) void mm5_kernel(
    const u16* A,
    const u16* W0, const u16* W1_, const u16* W2_, const u16* W3, const u16* W4,
    const float* b0, const float* b1, const float* b2, const float* b3, const float* b4,
    u16* C0, u16* C1, u16* C2, u16* C3, u16* C4, int M, int K) {
  __shared__ u16 As[128 * 64];
  __shared__ u16 Bs[128 * 64];
  int which = blockIdx.x / 6;
  int bn = (blockIdx.x % 6) * 128;
  const u16* Ws[5] = {W0, W1_, W2_, W3, W4};
  const float* bs[5] = {b0, b1, b2, b3, b4};
  u16* Cs[5] = {C0, C1, C2, C3, C4};
  if (which == 2 || which == 4)
    mm_core<0, 2>(A, Ws[which], bs[which], Cs[which], M, DMODEL, K, blockIdx.y * 128, bn, As, Bs);
  else
    mm_core<0, 1>(A, Ws[which], bs[which], Cs[which], M, DMODEL, K, blockIdx.y * 128, bn, As, Bs);
}

// ---------------- qg projection: grid (NGLOB, 6), 128 thr; one output col/thread ----
__global__ __launch_bounds__(128) void qg_proj_kernel(
    const float* __restrict__ h, const float* __restrict__ Wqg,
    const float* __restrict__ bqg, float* __restrict__ qg) {
  __shared__ float hs[DMODEL];
  int gi = blockIdx.x;
  int c0 = blockIdx.y * 128;
  int tid = threadIdx.x;
  const float* hrow = h + (size_t)gi * GSTRIDE * DMODEL;
  for (int i = tid; i < DMODEL; i += 128) hs[i] = hrow[i];
  __syncthreads();
  float a = bqg[c0 + tid];
  for (int k = 0; k < DMODEL; k++) a += hs[k] * Wqg[(size_t)k * DMODEL + c0 + tid];
  qg[gi * DMODEL + c0 + tid] = a;
}

// ---------------- sliding-window flash attention (MFMA) ----------------
__global__ __launch_bounds__(256) void sliding_attn_kernel(
    const u16* __restrict__ qb, const u16* __restrict__ kb,
    const u16* __restrict__ vt, const int* __restrict__ xmask,
    u16* __restrict__ ctx) {
  __shared__ u16 Ps[4 * 16 * 64];
  int hh = blockIdx.x >> 6;
  int q0 = (blockIdx.x & 63) * 64;
  int w = threadIdx.x >> 6, lane = threadIdx.x & 63;
  int lr = lane & 15, lg = lane >> 4;
  f32x4 zf = {0.f, 0.f, 0.f, 0.f};

  const u16* qptr = qb + (size_t)(q0 + w * 16 + lr) * DMODEL + hh * DHEAD;
  bf16x8 qf0 = *(const bf16x8*)(qptr + lg * 8);
  bf16x8 qf1 = *(const bf16x8*)(qptr + 32 + lg * 8);

  float m_run[4] = {-1e30f, -1e30f, -1e30f, -1e30f};
  float l_run[4] = {0.f, 0.f, 0.f, 0.f};
  f32x4 ctxa[4] = {zf, zf, zf, zf};

  // ---- global-key tile (8 keys; P cols 0..15 real, 16..31 zeroed for PV) ----
  {
    int krow = (lr < NGLOB) ? lr * GSTRIDE : 0;
    const u16* kp = kb + (size_t)krow * DMODEL + hh * DHEAD + lg * 8;
    f32x4 sa = __builtin_amdgcn_mfma_f32_16x16x32_bf16(qf0, *(const bf16x8*)kp, zf, 0, 0, 0);
    sa = __builtin_amdgcn_mfma_f32_16x16x32_bf16(qf1, *(const bf16x8*)(kp + 32), sa, 0, 0, 0);
    float p0[4], tmax[4];
#pragma unroll
    for (int r = 0; r < 4; r++) {
      float s = (lr < NGLOB) ? sa[r] * 0.125f : -1e30f;
      p0[r] = s; tmax[r] = s;
    }
#pragma unroll
    for (int o = 8; o; o >>= 1)
#pragma unroll
      for (int r = 0; r < 4; r++) tmax[r] = fmaxf(tmax[r], __shfl_xor(tmax[r], o));
    float tsum[4];
#pragma unroll
    for (int r = 0; r < 4; r++) {
      float mn = fmaxf(m_run[r], tmax[r]);
      m_run[r] = mn;
      p0[r] = __expf(p0[r] - mn);
      tsum[r] = p0[r];
    }
#pragma unroll
    for (int o = 8; o; o >>= 1)
#pragma unroll
      for (int r = 0; r < 4; r++) tsum[r] += __shfl_xor(tsum[r], o);
#pragma unroll
    for (int r = 0; r < 4; r++) l_run[r] = tsum[r];
#pragma unroll
    for (int r = 0; r < 4; r++) {
      int qi = lg * 4 + r;
      Ps[w * 1024 + qi * 64 + (((lr >> 3) ^ (qi & 7)) * 8) + (lr & 7)] = f2bf(p0[r]);
      int k2 = 16 + lr;
      Ps[w * 1024 + qi * 64 + (((k2 >> 3) ^ (qi & 7)) * 8) + (k2 & 7)] = 0;
    }
    bf16x8 pf = *(const bf16x8*)&Ps[w * 1024 + lr * 64 + ((lg ^ (lr & 7)) * 8)];
#pragma unroll
    for (int c2 = 0; c2 < 4; c2++) {
      bf16x8 vg8 = {0, 0, 0, 0, 0, 0, 0, 0};
      if (lg == 0) {
        const u16* vrow = vt + (size_t)(hh * DHEAD + c2 * 16 + lr) * S_LEN;
#pragma unroll
        for (int j = 0; j < 8; j++) vg8[j] = (short)vrow[(size_t)j * GSTRIDE];
      }
      ctxa[c2] = __builtin_amdgcn_mfma_f32_16x16x32_bf16(pf, vg8, ctxa[c2], 0, 0, 0);
    }
  }

  // ---- 9 band tiles of 64 keys ----
  for (int tt = 0; tt < 9; tt++) {
    int base = q0 - WIN + tt * 64;
    if (base + 63 < 0 || base >= S_LEN) continue;
    f32x4 sa[4];
    int keyc[4]; bool vc[4];
#pragma unroll
    for (int c = 0; c < 4; c++) {
      int key = base + c * 16 + lr;
      int krow = key < 0 ? 0 : (key > S_LEN - 1 ? S_LEN - 1 : key);
      vc[c] = (key >= 0) && (key < S_LEN) && ((key & (GSTRIDE - 1)) != 0) && (xmask[krow] != 0);
      keyc[c] = key;
      const u16* kp = kb + (size_t)krow * DMODEL + hh * DHEAD + lg * 8;
      sa[c] = __builtin_amdgcn_mfma_f32_16x16x32_bf16(qf0, *(const bf16x8*)kp, zf, 0, 0, 0);
      sa[c] = __builtin_amdgcn_mfma_f32_16x16x32_bf16(qf1, *(const bf16x8*)(kp + 32), sa[c], 0, 0, 0);
    }
    float p[4][4], tmax[4] = {-1e30f, -1e30f, -1e30f, -1e30f};
#pragma unroll
    for (int c = 0; c < 4; c++)
#pragma unroll
      for (int r = 0; r < 4; r++) {
        int qrow = q0 + w * 16 + lg * 4 + r;
        int dd = keyc[c] - qrow;
        float s = (vc[c] && dd >= -WIN && dd <= WIN) ? sa[c][r] * 0.125f : -1e30f;
        p[c][r] = s;
        tmax[r] = fmaxf(tmax[r], s);
      }
#pragma unroll
    for (int o = 8; o; o >>= 1)
#pragma unroll
      for (int r = 0; r < 4; r++) tmax[r] = fmaxf(tmax[r], __shfl_xor(tmax[r], o));
    float sc[4], tsum[4] = {0.f, 0.f, 0.f, 0.f};
#pragma unroll
    for (int r = 0; r < 4; r++) {
      float mn = fmaxf(m_run[r], tmax[r]);
      sc[r] = __expf(m_run[r] - mn);
      m_run[r] = mn;
    }
#pragma unroll
    for (int c = 0; c < 4; c++)
#pragma unroll
      for (int r = 0; r < 4; r++) {
        p[c][r] = __expf(p[c][r] - m_run[r]);
        tsum[r] += p[c][r];
      }
#pragma unroll
    for (int o = 8; o; o >>= 1)
#pragma unroll
      for (int r = 0; r < 4; r++) tsum[r] += __shfl_xor(tsum[r], o);
#pragma unroll
    for (int r = 0; r < 4; r++) l_run[r] = l_run[r] * sc[r] + tsum[r];
#pragma unroll
    for (int c2 = 0; c2 < 4; c2++)
#pragma unroll
      for (int r = 0; r < 4; r++) ctxa[c2][r] *= sc[r];
#pragma unroll
    for (int c = 0; c < 4; c++)
#pragma unroll
      for (int r = 0; r < 4; r++) {
        int qi = lg * 4 + r, k64 = c * 16 + lr;
        Ps[w * 1024 + qi * 64 + (((k64 >> 3) ^ (qi & 7)) * 8) + (k64 & 7)] = f2bf(p[c][r]);
      }
#pragma unroll
    for (int ks = 0; ks < 2; ks++) {
      bf16x8 pf = *(const bf16x8*)&Ps[w * 1024 + lr * 64 + (((ks * 4 + lg) ^ (lr & 7)) * 8)];
      int kstart = base + ks * 32 + lg * 8;
      int kc = kstart < 0 ? 0 : (kstart > S_LEN - 8 ? S_LEN - 8 : kstart);
#pragma unroll
      for (int c2 = 0; c2 < 4; c2++) {
        const u16* vp = vt + (size_t)(hh * DHEAD + c2 * 16 + lr) * S_LEN + kc;
        ctxa[c2] = __builtin_amdgcn_mfma_f32_16x16x32_bf16(pf, *(const bf16x8*)vp, ctxa[c2], 0, 0, 0);
      }
    }
  }

#pragma unroll
  for (int c2 = 0; c2 < 4; c2++)
#pragma unroll
    for (int r = 0; r < 4; r++) {
      int qrow = q0 + w * 16 + lg * 4 + r;
      ctx[(size_t)qrow * DMODEL + hh * DHEAD + c2 * 16 + lr] = f2bf(ctxa[c2][r] / l_run[r]);
    }
}

// ---------------- global-token attention, phase 1 ----------------
__global__ __launch_bounds__(256) void gattn_part_kernel(
    const float* __restrict__ qg, const u16* __restrict__ kg,
    const u16* __restrict__ vgt, const int* __restrict__ xmask,
    float* __restrict__ pm, float* __restrict__ pl, float* __restrict__ pacc) {
  __shared__ u16 Ps[4 * 16 * 64];
  int hh = blockIdx.x;
  int c  = blockIdx.y;
  int w = threadIdx.x >> 6, lane = threadIdx.x & 63;
  int lr = lane & 15, lg = lane >> 4;
  int base = c * 256 + w * 64;
  f32x4 zf = {0.f, 0.f, 0.f, 0.f};

  bf16x8 qf0, qf1;
  {
    const float* qp = qg + (size_t)(lr & 7) * DMODEL + hh * DHEAD;
    bool real = lr < 8;
#pragma unroll
    for (int j = 0; j < 8; j++) {
      qf0[j] = real ? (short)f2bf(0.125f * qp[lg * 8 + j]) : (short)0;
      qf1[j] = real ? (short)f2bf(0.125f * qp[32 + lg * 8 + j]) : (short)0;
    }
  }

  f32x4 sa[4];
  bool vc[4];
#pragma unroll
  for (int st = 0; st < 4; st++) {
    int key = base + st * 16 + lr;
    vc[st] = (xmask[key] != 0) || ((key & (GSTRIDE - 1)) == 0);
    const u16* kp = kg + (size_t)key * DMODEL + hh * DHEAD + lg * 8;
    sa[st] = __builtin_amdgcn_mfma_f32_16x16x32_bf16(qf0, *(const bf16x8*)kp, zf, 0, 0, 0);
    sa[st] = __builtin_amdgcn_mfma_f32_16x16x32_bf16(qf1, *(const bf16x8*)(kp + 32), sa[st], 0, 0, 0);
  }
  float p[4][4], tmax[4] = {-1e30f, -1e30f, -1e30f, -1e30f};
#pragma unroll
  for (int st = 0; st < 4; st++)
#pragma unroll
    for (int r = 0; r < 4; r++) {
      float s = vc[st] ? sa[st][r] : -1e30f;
      p[st][r] = s;
      tmax[r] = fmaxf(tmax[r], s);
    }
#pragma unroll
  for (int o = 8; o; o >>= 1)
#pragma unroll
    for (int r = 0; r < 4; r++) tmax[r] = fmaxf(tmax[r], __shfl_xor(tmax[r], o));
  float tsum[4] = {0.f, 0.f, 0.f, 0.f};
#pragma unroll
  for (int st = 0; st < 4; st++)
#pragma unroll
    for (int r = 0; r < 4; r++) {
      float pv = vc[st] ? __expf(p[st][r] - tmax[r]) : 0.f;
      p[st][r] = pv;
      tsum[r] += pv;
    }
#pragma unroll
  for (int o = 8; o; o >>= 1)
#pragma unroll
    for (int r = 0; r < 4; r++) tsum[r] += __shfl_xor(tsum[r], o);
#pragma unroll
  for (int st = 0; st < 4; st++)
#pragma unroll
    for (int r = 0; r < 4; r++) {
      int qi = lg * 4 + r, k64 = st * 16 + lr;
      Ps[w * 1024 + qi * 64 + (((k64 >> 3) ^ (qi & 7)) * 8) + (k64 & 7)] = f2bf(p[st][r]);
    }
  f32x4 ctxa[4] = {zf, zf, zf, zf};
#pragma unroll
  for (int ks = 0; ks < 2; ks++) {
    bf16x8 pf = *(const bf16x8*)&Ps[w * 1024 + lr * 64 + (((ks * 4 + lg) ^ (lr & 7)) * 8)];
    int kstart = base + ks * 32 + lg * 8;
#pragma unroll
    for (int c2 = 0; c2 < 4; c2++) {
      const u16* vp = vgt + (size_t)(hh * DHEAD + c2 * 16 + lr) * S_LEN + kstart;
      ctxa[c2] = __builtin_amdgcn_mfma_f32_16x16x32_bf16(pf, *(const bf16x8*)vp, ctxa[c2], 0, 0, 0);
    }
  }
  int pidx = (hh * 16 + c) * 4 + w;
  if (lg < 2) {
#pragma unroll
    for (int r = 0; r < 4; r++) {
      int q = lg * 4 + r;
#pragma unroll
      for (int c2 = 0; c2 < 4; c2++)
        pacc[(size_t)pidx * 512 + q * 64 + c2 * 16 + lr] = ctxa[c2][r];
      if (lr == 0) {
        pm[pidx * 8 + q] = tmax[r];
        pl[pidx * 8 + q] = tsum[r];
      }
    }
  }
}

// ---------------- global-token attention, phase 2 ----------------
__global__ __launch_bounds__(64) void gattn_comb_kernel(
    const float* __restrict__ pm, const float* __restrict__ pl,
    const float* __restrict__ pacc, u16* __restrict__ ctx) {
  int gi = blockIdx.x / NHEAD, hh = blockIdx.x % NHEAD;
  int d = threadIdx.x;
  float M = -1e30f, L = 0.f, A = 0.f;
  for (int i = 0; i < 64; i++) {
    int pidx = hh * 64 + i;
    float m_i = pm[pidx * 8 + gi];
    float l_i = pl[pidx * 8 + gi];
    float a_i = pacc[(size_t)pidx * 512 + gi * 64 + d];
    if (m_i > M) {
      float sc = __expf(M - m_i);
      A = A * sc + a_i;
      L = L * sc + l_i;
      M = m_i;
    } else {
      float sc = __expf(m_i - M);
      A += a_i * sc;
      L += l_i * sc;
    }
  }
  ctx[(size_t)gi * GSTRIDE * DMODEL + hh * DHEAD + d] = f2bf(A / L);
}

// ---------------- CLS pooling + output projection -----------------
__global__ __launch_bounds__(128) void cls_out_kernel(
    const float* __restrict__ h, const float* __restrict__ ow,
    const float* __restrict__ ob, float* __restrict__ y) {
  __shared__ float hs[DMODEL];
  int wi = blockIdx.x;
  int tid = threadIdx.x;
  for (int i = tid; i < DMODEL; i += 128) hs[i] = h[(size_t)wi * GSTRIDE * DMODEL + i];
  __syncthreads();
  float a = ob[tid];
  for (int d = 0; d < DMODEL; d++) a += hs[d] * ow[d * 128 + tid];
  y[wi * 128 + tid] = a;
}

// ---------------- host launch ----------------
extern "C" void kernel_launch(void* const* d_in, const int* in_sizes, int n_in,
                              void* d_out, int out_size, void* d_ws, size_t ws_size,
                              hipStream_t stream) {
  const int*   x      = (const int*)d_in[0];
  const int*   xmask  = (const int*)d_in[1];
  const float* wemb   = (const float*)d_in[2];
  const float* pemb   = (const float*)d_in[3];
  const float* emb_g  = (const float*)d_in[4];
  const float* emb_b  = (const float*)d_in[5];
  const float* Wq     = (const float*)d_in[6];
  const float* bq     = (const float*)d_in[7];
  const float* Wk     = (const float*)d_in[8];
  const float* bk     = (const float*)d_in[9];
  const float* Wv     = (const float*)d_in[10];
  const float* bv     = (const float*)d_in[11];
  const float* Wo     = (const float*)d_in[12];
  const float* bo     = (const float*)d_in[13];
  const float* Wqg    = (const float*)d_in[14];
  const float* bqg    = (const float*)d_in[15];
  const float* Wkg    = (const float*)d_in[16];
  const float* bkg    = (const float*)d_in[17];
  const float* Wvg    = (const float*)d_in[18];
  const float* bvg    = (const float*)d_in[19];
  const float* ln1_g  = (const float*)d_in[20];
  const float* ln1_b  = (const float*)d_in[21];
  const float* W1     = (const float*)d_in[22];
  const float* b1     = (const float*)d_in[23];
  const float* W2     = (const float*)d_in[24];
  const float* b2     = (const float*)d_in[25];
  const float* ln2_g  = (const float*)d_in[26];
  const float* ln2_b  = (const float*)d_in[27];
  const float* out_w  = (const float*)d_in[28];
  const float* out_b  = (const float*)d_in[29];

  char* wsp = (char*)d_ws;
  float* h   = (float*)wsp;  wsp += (size_t)S_LEN * DMODEL * 4;
  float* tmp = (float*)wsp;  wsp += (size_t)S_LEN * DMODEL * 4;
  u16* hb  = (u16*)wsp;      wsp += (size_t)S_LEN * DMODEL * 2;
  u16* ctx = (u16*)wsp;      wsp += (size_t)S_LEN * DMODEL * 2;
  u16* qb  = (u16*)wsp;      wsp += (size_t)S_LEN * DMODEL * 2;
  u16* kb  = (u16*)wsp;      wsp += (size_t)S_LEN * DMODEL * 2;
  u16* vt  = (u16*)wsp;      wsp += (size_t)S_LEN * DMODEL * 2;
  u16* kgb = (u16*)wsp;      wsp += (size_t)S_LEN * DMODEL * 2;
  u16* vgt = (u16*)wsp;      wsp += (size_t)S_LEN * DMODEL * 2;
  u16* mid = (u16*)wsp;      wsp += (size_t)S_LEN * FDIM * 2;
  float* qgb = (float*)wsp;  wsp += (size_t)NGLOB * DMODEL * 4;
  float* pm = (float*)wsp;   wsp += (size_t)768 * 8 * 4;
  float* pl = (float*)wsp;   wsp += (size_t)768 * 8 * 4;
  float* pacc = (float*)wsp; wsp += (size_t)768 * 512 * 4;
  u16* wtb = (u16*)wsp;      wsp += WSTRIDE * NLAYER * 2;

  embed_ln_kernel<<<S_LEN, 256, 0, stream>>>(x, wemb, pemb, emb_g, emb_b, h, hb);
  convw_kernel<<<dim3(2016, NLAYER), 256, 0, stream>>>(Wq, Wk, Wv, Wkg, Wvg, Wo, W1, W2, wtb);

  for (int l = 0; l < NLAYER; l++) {
    const float* bql  = bq  + (size_t)l * DMODEL;
    const float* bkl  = bk  + (size_t)l * DMODEL;
    const float* bvl  = bv  + (size_t)l * DMODEL;
    const float* bol  = bo  + (size_t)l * DMODEL;
    const float* wqg  = Wqg + (size_t)l * DD_;
    const float* bqgl = bqg + (size_t)l * DMODEL;
    const float* bkgl = bkg + (size_t)l * DMODEL;
    const float* bvgl = bvg + (size_t)l * DMODEL;
    const float* b1l  = b1  + (size_t)l * FDIM;
    const float* b2l  = b2  + (size_t)l * DMODEL;
    u16* base = wtb + (size_t)l * WSTRIDE;
    u16* wqT  = base;
    u16* wkT  = base + 1 * DD_;
    u16* wvT  = base + 2 * DD_;
    u16* wkgT = base + 3 * DD_;
    u16* wvgT = base + 4 * DD_;
    u16* woT  = base + 5 * DD_;
    u16* w1T  = base + 6 * DD_;
    u16* w2T  = base + 6 * DD_ + DF_;

    mm5_kernel<<<dim3(30, 32), 256, 0, stream>>>(
        hb, wqT, wkT, wvT, wkgT, wvgT, bql, bkl, bvl, bkgl, bvgl,
        qb, kb, vt, kgb, vgt, S_LEN, DMODEL);
    qg_proj_kernel<<<dim3(NGLOB, 6), 128, 0, stream>>>(h, wqg, bqgl, qgb);

    sliding_attn_kernel<<<NHEAD * 64, 256, 0, stream>>>(qb, kb, vt, xmask, ctx);
    gattn_part_kernel<<<dim3(NHEAD, 16), 256, 0, stream>>>(qgb, kgb, vgt, xmask, pm, pl, pacc);
    gattn_comb_kernel<<<NGLOB * NHEAD, 64, 0, stream>>>(pm, pl, pacc, ctx);

    mm_kernel<0, 0><<<dim3(6, 32), 256, 0, stream>>>(ctx, woT, bol, tmp, S_LEN, DMODEL, DMODEL);
    add_ln_kernel<<<S_LEN, 256, 0, stream>>>(h, tmp, ln1_g + (size_t)l * DMODEL,
                                             ln1_b + (size_t)l * DMODEL, hb);

    mm_kernel<1, 1><<<dim3(24, 32), 256, 0, stream>>>(hb, w1T, b1l, mid, S_LEN, FDIM, DMODEL);
    mm_kernel<0, 0><<<dim3(6, 32), 256, 0, stream>>>(mid, w2T, b2l, tmp, S_LEN, DMODEL, FDIM);
    add_ln_kernel<<<S_LEN, 256, 0, stream>>>(h, tmp, ln2_g + (size_t)l * DMODEL,
                                             ln2_b + (size_t)l * DMODEL, hb);
  }

  cls_out_kernel<<<NGLOB, 128, 0, stream>>>(h, out_w, out_b, (float*)d_out);
}